// Round 8
// baseline (295.519 us; speedup 1.0000x reference)
//
#include <hip/hip_runtime.h>

// HolographicBlock: B=2, S=2048, D=1024, R=64, H=8, HD=128
// Projections = bf16 MFMA GEMMs (K-split down-proj, f32 partials).
// Attention = barrier-free per-wave flash attention: 1 wave = 16 q-rows,
// K/V direct from L2, per-wave private LDS P-bounce, 2048 independent waves.

#define Bn 2
#define Sn 2048
#define Dn 1024
#define Rn 64
#define Hn 8
#define HDn 128
#define Mn (Bn*Sn)   // 4096 rows
#define TSTRIDE ((size_t)Mn * Rn)

typedef __bf16 bf16x8 __attribute__((ext_vector_type(8)));
typedef float f32x4 __attribute__((ext_vector_type(4)));

__device__ __forceinline__ float bf2f(unsigned short u){
    union { unsigned int i; float f; } x; x.i = ((unsigned int)u) << 16; return x.f;
}
__device__ __forceinline__ unsigned short f2bf(float f){
    union { float f; unsigned int i; } x; x.f = f;
    unsigned int r = x.i + 0x7fffu + ((x.i >> 16) & 1u);
    return (unsigned short)(r >> 16);
}
__device__ __forceinline__ unsigned int pk2(float a, float b){
    return (unsigned int)f2bf(a) | ((unsigned int)f2bf(b) << 16);
}

// ---------------- prep: bf16 transposed weights + rope table
__global__ __launch_bounds__(256) void prep_g(const float* __restrict__ A,
                                              const float* __restrict__ Bsrc,
                                              const float* __restrict__ Cq, const float* __restrict__ Ck,
                                              const float* __restrict__ Cv, const float* __restrict__ Co,
                                              const float* __restrict__ Cfc, const float* __restrict__ Cpr,
                                              const float* __restrict__ s1, const float* __restrict__ s2,
                                              unsigned short* __restrict__ At0, unsigned short* __restrict__ At1,
                                              unsigned short* __restrict__ At2,
                                              unsigned short* __restrict__ Btq, unsigned short* __restrict__ Btk,
                                              unsigned short* __restrict__ Btv, unsigned short* __restrict__ Bto,
                                              unsigned short* __restrict__ Btfc, unsigned short* __restrict__ Btpr,
                                              float2* __restrict__ rt){
    int idx = blockIdx.x * 256 + threadIdx.x;
    if (idx < 3 * 65536){
        int v = idx >> 16, e = idx & 65535;
        int r = e >> 10, d = e & 1023;
        float sc = (v == 0) ? 1.f : (v == 1 ? s1[d] : s2[d]);
        unsigned short val = f2bf(A[d * 64 + r] * sc);
        (v == 0 ? At0 : v == 1 ? At1 : At2)[e] = val;
    } else if (idx < 9 * 65536){
        int v = (idx - 3 * 65536) >> 16, e = idx & 65535;
        int d = e >> 6, r = e & 63;
        const float* C = v==0?Cq : v==1?Ck : v==2?Cv : v==3?Co : v==4?Cfc : Cpr;
        unsigned short val = f2bf(Bsrc[r * 1024 + d] * C[r]);
        (v==0?Btq : v==1?Btk : v==2?Btv : v==3?Bto : v==4?Btfc : Btpr)[e] = val;
    } else if (idx < 9 * 65536 + Sn * 64){
        int e = idx - 9 * 65536;
        int s = e >> 6, f = e & 63;
        float inv = exp2f(-(float)f * (13.287712379549449f / 64.0f));
        float fr = (float)s * inv;
        float sn, cs; sincosf(fr, &sn, &cs);
        rt[e] = make_float2(cs, sn);
    }
}

// ---------------- down GEMM (K-split): tpart[sp][m][r] = sum_{d in split} in[m][d] * At[r][d]
template<int IN_BF16, int WRITE_SS>
__global__ __launch_bounds__(256) void down_g(const void* __restrict__ inp,
                                              const unsigned short* __restrict__ At,
                                              float* __restrict__ tpart,
                                              float* __restrict__ sspart){
    __shared__ char xt[8192];
    __shared__ char at[8192];
    int tid = threadIdx.x;
    int m0 = blockIdx.x * 64, sp = blockIdx.y;
    int row = tid >> 2, q4 = tid & 3;
    int w = tid >> 6, lane = tid & 63, l4 = lane >> 4, lm = lane & 15;
    int swz = (row & 7) << 4;
    float ss = 0.f;
    f32x4 acc[4];
    #pragma unroll
    for (int nt = 0; nt < 4; ++nt) acc[nt] = (f32x4){0.f,0.f,0.f,0.f};

    float4 xr[4]; uint4 xrb[2]; uint4 ar[2];
    #define LOADC(c) { int k0 = sp * 256 + (c) * 64; \
        if (!IN_BF16){ const float4* s = (const float4*)((const float*)inp + (size_t)(m0+row)*1024 + k0 + q4*16); \
            xr[0]=s[0]; xr[1]=s[1]; xr[2]=s[2]; xr[3]=s[3]; } \
        else { const uint4* s = (const uint4*)((const unsigned short*)inp + (size_t)(m0+row)*1024 + k0 + q4*16); \
            xrb[0]=s[0]; xrb[1]=s[1]; } \
        const uint4* a = (const uint4*)(At + (size_t)row*1024 + k0 + q4*16); \
        ar[0]=a[0]; ar[1]=a[1]; }

    LOADC(0);
    for (int c = 0; c < 4; ++c){
        int b0 = row * 128 + ((q4 * 32) ^ swz);
        int b1 = row * 128 + ((q4 * 32 + 16) ^ swz);
        if (!IN_BF16){
            if (WRITE_SS){
                #pragma unroll
                for (int i = 0; i < 4; ++i)
                    ss += xr[i].x*xr[i].x + xr[i].y*xr[i].y + xr[i].z*xr[i].z + xr[i].w*xr[i].w;
            }
            uint4 p0 = {pk2(xr[0].x,xr[0].y), pk2(xr[0].z,xr[0].w), pk2(xr[1].x,xr[1].y), pk2(xr[1].z,xr[1].w)};
            uint4 p1 = {pk2(xr[2].x,xr[2].y), pk2(xr[2].z,xr[2].w), pk2(xr[3].x,xr[3].y), pk2(xr[3].z,xr[3].w)};
            *(uint4*)(xt + b0) = p0; *(uint4*)(xt + b1) = p1;
        } else {
            *(uint4*)(xt + b0) = xrb[0]; *(uint4*)(xt + b1) = xrb[1];
        }
        *(uint4*)(at + b0) = ar[0]; *(uint4*)(at + b1) = ar[1];
        __syncthreads();
        if (c < 3) LOADC(c + 1);
        #pragma unroll
        for (int ks = 0; ks < 2; ++ks){
            int arow = 16 * w + lm;
            bf16x8 af = *(const bf16x8*)(xt + arow * 128 + ((ks*64 + l4*16) ^ ((arow & 7) << 4)));
            #pragma unroll
            for (int nt = 0; nt < 4; ++nt){
                int brow = nt * 16 + lm;
                bf16x8 bf = *(const bf16x8*)(at + brow * 128 + ((ks*64 + l4*16) ^ ((brow & 7) << 4)));
                acc[nt] = __builtin_amdgcn_mfma_f32_16x16x32_bf16(af, bf, acc[nt], 0, 0, 0);
            }
        }
        __syncthreads();
    }
    #undef LOADC
    if (!IN_BF16 && WRITE_SS){
        ss += __shfl_xor(ss, 1); ss += __shfl_xor(ss, 2);
        if (q4 == 0) sspart[sp * Mn + m0 + row] = ss;
    }
    #pragma unroll
    for (int nt = 0; nt < 4; ++nt)
        #pragma unroll
        for (int r = 0; r < 4; ++r){
            int ml = 16 * w + 4 * l4 + r;
            tpart[(size_t)sp * TSTRIDE + (size_t)(m0 + ml) * 64 + nt * 16 + lm] = acc[nt][r];
        }
}

// ---------------- stage t tile (sum 4 K-split partials, optional rms scale) into swizzled LDS
template<int DORMS>
__device__ __forceinline__ void stage_t(char* tt, const float* __restrict__ tpart,
                                        const float* __restrict__ sspart, int m0, int tid){
    int row = tid >> 2, q4 = tid & 3;
    const float* bp = tpart + (size_t)(m0 + row) * 64 + q4 * 16;
    float4 s[4];
    #pragma unroll
    for (int i = 0; i < 4; ++i){
        float4 a = ((const float4*)(bp + 0 * TSTRIDE))[i];
        float4 b = ((const float4*)(bp + 1 * TSTRIDE))[i];
        float4 c = ((const float4*)(bp + 2 * TSTRIDE))[i];
        float4 d = ((const float4*)(bp + 3 * TSTRIDE))[i];
        s[i] = make_float4(a.x+b.x+c.x+d.x, a.y+b.y+c.y+d.y, a.z+b.z+c.z+d.z, a.w+b.w+c.w+d.w);
    }
    float rr = 1.f;
    if (DORMS){
        int m = m0 + row;
        float ssum = sspart[m] + sspart[Mn + m] + sspart[2*Mn + m] + sspart[3*Mn + m];
        rr = rsqrtf(ssum * (1.f / 1024.f) + 1.1920929e-07f);
    }
    #pragma unroll
    for (int i = 0; i < 4; ++i){ s[i].x*=rr; s[i].y*=rr; s[i].z*=rr; s[i].w*=rr; }
    int swz = (row & 7) << 4;
    uint4 p0 = {pk2(s[0].x,s[0].y), pk2(s[0].z,s[0].w), pk2(s[1].x,s[1].y), pk2(s[1].z,s[1].w)};
    uint4 p1 = {pk2(s[2].x,s[2].y), pk2(s[2].z,s[2].w), pk2(s[3].x,s[3].y), pk2(s[3].z,s[3].w)};
    *(uint4*)(tt + row * 128 + ((q4 * 32) ^ swz)) = p0;
    *(uint4*)(tt + row * 128 + ((q4 * 32 + 16) ^ swz)) = p1;
}

// ---------------- up GEMM: M-tile 32 x N-chunk 256, K=64
template<int SILU, int HASBASE, int OUT_BF16, int DORMS>
__global__ __launch_bounds__(256) void up_g(const float* __restrict__ tpart,
                                            const float* __restrict__ sspart,
                                            const unsigned short* __restrict__ Bt,
                                            const float* base,
                                            void* __restrict__ outp){
    __shared__ char tt[4096];
    __shared__ char bb[32768];
    int tid = threadIdx.x;
    int m0 = blockIdx.x * 32, n0 = blockIdx.y * 256;
    int w = tid >> 6, lane = tid & 63, l4 = lane >> 4, lm = lane & 15;
    int wm = w & 1, wn = w >> 1;
    if (tid < 128) stage_t<DORMS>(tt, tpart, sspart, m0, tid);
    {
        const uint4* s = (const uint4*)(Bt + (size_t)(n0 + tid) * 64);
        #pragma unroll
        for (int j = 0; j < 8; ++j){
            uint4 v = s[j];
            *(uint4*)(bb + tid * 128 + ((j * 16) ^ ((tid & 7) << 4))) = v;
        }
    }
    __syncthreads();
    bf16x8 af[2];
    #pragma unroll
    for (int ks = 0; ks < 2; ++ks){
        int arow = 16 * wm + lm;
        af[ks] = *(const bf16x8*)(tt + arow * 128 + ((ks*64 + l4*16) ^ ((arow & 7) << 4)));
    }
    f32x4 acc[8];
    #pragma unroll
    for (int nt = 0; nt < 8; ++nt) acc[nt] = (f32x4){0.f,0.f,0.f,0.f};
    #pragma unroll
    for (int nt = 0; nt < 8; ++nt){
        int brow = wn * 128 + nt * 16 + lm;
        #pragma unroll
        for (int ks = 0; ks < 2; ++ks){
            bf16x8 bf = *(const bf16x8*)(bb + brow * 128 + ((ks*64 + l4*16) ^ ((brow & 7) << 4)));
            acc[nt] = __builtin_amdgcn_mfma_f32_16x16x32_bf16(af[ks], bf, acc[nt], 0, 0, 0);
        }
    }
    #pragma unroll
    for (int nt = 0; nt < 8; ++nt)
        #pragma unroll
        for (int r = 0; r < 4; ++r){
            int m = m0 + 16 * wm + 4 * l4 + r;
            int n = n0 + wn * 128 + nt * 16 + lm;
            float v = acc[nt][r];
            if (SILU) v = v / (1.f + __expf(-v));
            if (HASBASE) v += base[(size_t)m * 1024 + n];
            if (OUT_BF16) ((unsigned short*)outp)[(size_t)m * 1024 + n] = f2bf(v);
            else          ((float*)outp)[(size_t)m * 1024 + n] = v;
        }
}

// ---------------- fused QKV up-proj + RoPE (q,k row-major [bh,s,hd]; v transposed [bh,d,s])
__global__ __launch_bounds__(256) void qkv_g(const float* __restrict__ tpart,
                                             const float* __restrict__ sspart,
                                             const unsigned short* __restrict__ Btq,
                                             const unsigned short* __restrict__ Btk,
                                             const unsigned short* __restrict__ Btv,
                                             const float2* __restrict__ rt,
                                             unsigned short* __restrict__ qout,
                                             unsigned short* __restrict__ kout,
                                             unsigned short* __restrict__ vtout){
    __shared__ char tt[8192];
    __shared__ char bb[32768];
    int tid = threadIdx.x;
    int m0 = blockIdx.x * 64, n0 = blockIdx.y * 256;
    int b = m0 >> 11, s0 = m0 & (Sn - 1);
    int h0 = n0 >> 7;
    int w = tid >> 6, lane = tid & 63, l4 = lane >> 4, lm = lane & 15;
    stage_t<1>(tt, tpart, sspart, m0, tid);
    #define STAGE_B(SRC) { const uint4* s = (const uint4*)((SRC) + (size_t)(n0 + tid) * 64); \
        _Pragma("unroll") for (int j = 0; j < 8; ++j){ uint4 v = s[j]; \
            *(uint4*)(bb + tid * 128 + ((j * 16) ^ ((tid & 7) << 4))) = v; } }
    STAGE_B(Btq);
    __syncthreads();
    bf16x8 af[2];
    #pragma unroll
    for (int ks = 0; ks < 2; ++ks){
        int arow = 16 * w + lm;
        af[ks] = *(const bf16x8*)(tt + arow * 128 + ((ks*64 + l4*16) ^ ((arow & 7) << 4)));
    }
    f32x4 acc[16];
    float2 cs[4][4];
    #pragma unroll
    for (int ntb = 0; ntb < 4; ++ntb)
        #pragma unroll
        for (int r = 0; r < 4; ++r)
            cs[ntb][r] = rt[(size_t)(s0 + 16*w + 4*l4 + r) * 64 + ntb * 16 + lm];

    #define MMUL() { _Pragma("unroll") for (int nt = 0; nt < 16; ++nt) acc[nt] = (f32x4){0.f,0.f,0.f,0.f}; \
        _Pragma("unroll") for (int nt = 0; nt < 16; ++nt){ int brow = nt * 16 + lm; \
            _Pragma("unroll") for (int ks = 0; ks < 2; ++ks){ \
                bf16x8 bf = *(const bf16x8*)(bb + brow * 128 + ((ks*64 + l4*16) ^ ((brow & 7) << 4))); \
                acc[nt] = __builtin_amdgcn_mfma_f32_16x16x32_bf16(af[ks], bf, acc[nt], 0, 0, 0); } } }

    #define ROPE() { _Pragma("unroll") for (int g = 0; g < 2; ++g) \
        _Pragma("unroll") for (int ntb = 0; ntb < 4; ++ntb){ int lo = g*8 + ntb, hi = lo + 4; \
            _Pragma("unroll") for (int r = 0; r < 4; ++r){ float2 c = cs[ntb][r]; \
                float a = acc[lo][r], bq = acc[hi][r]; \
                acc[lo][r] = a * c.x + bq * c.y; acc[hi][r] = -a * c.y + bq * c.x; } } }

    #define BOUNCE_STORE(DST) { \
        _Pragma("unroll") for (int nt = 0; nt < 16; ++nt) \
            _Pragma("unroll") for (int r = 0; r < 4; ++r){ \
                int nl = nt * 16 + lm, ml2 = 16 * w + 4 * l4 + r; \
                *(unsigned short*)(bb + ml2 * 512 + ((nl * 2) ^ ((ml2 & 7) << 4))) = f2bf(acc[nt][r]); } \
        __syncthreads(); \
        { int ml = tid >> 2, seg = tid & 3; \
          int head = h0 + (seg >> 1), hd0 = (seg & 1) * 64; \
          size_t dstbase = (((size_t)(b * 8 + head) * Sn + (s0 + ml)) * 128 + hd0); \
          _Pragma("unroll") for (int j = 0; j < 8; ++j){ \
              uint4 v = *(const uint4*)(bb + ml * 512 + ((seg * 128 + j * 16) ^ ((ml & 7) << 4))); \
              *(uint4*)((DST) + dstbase + j * 8) = v; } } \
        __syncthreads(); }

    // ---- Q
    MMUL(); ROPE();
    __syncthreads();
    BOUNCE_STORE(qout);
    // ---- K
    STAGE_B(Btk);
    __syncthreads();
    MMUL(); ROPE();
    __syncthreads();
    BOUNCE_STORE(kout);
    // ---- V (transposed store)
    STAGE_B(Btv);
    __syncthreads();
    MMUL();
    __syncthreads();
    #pragma unroll
    for (int nt = 0; nt < 16; ++nt)
        #pragma unroll
        for (int r = 0; r < 4; ++r){
            int nl = nt * 16 + lm, ml2 = 16 * w + 4 * l4 + r;
            *(unsigned short*)(bb + nl * 128 + ((ml2 * 2) ^ ((nl & 7) << 4))) = f2bf(acc[nt][r]);
        }
    __syncthreads();
    {
        int head = h0 + (tid >> 7), d = tid & 127;
        size_t dstbase = (((size_t)(b * 8 + head) * 128 + d) * Sn + s0);
        #pragma unroll
        for (int j = 0; j < 8; ++j){
            uint4 v = *(const uint4*)(bb + tid * 128 + ((j * 16) ^ ((tid & 7) << 4)));
            *(uint4*)(vtout + dstbase + j * 8) = v;
        }
    }
    #undef STAGE_B
    #undef MMUL
    #undef ROPE
    #undef BOUNCE_STORE
}

// ---------------- barrier-free per-wave flash attention
// 512 blocks x 4 waves = 2048 independent waves; wave = 16 q-rows, heavy-first.
// K/V read directly from global (L2-resident); P via per-wave private LDS.
__global__ __launch_bounds__(256) void attn3_kernel(const unsigned short* __restrict__ qb,
                                                    const unsigned short* __restrict__ kb,
                                                    const unsigned short* __restrict__ vtb,
                                                    unsigned short* __restrict__ ybf){
    __shared__ char pls[4][2048];
    int tid = threadIdx.x;
    int w = tid >> 6, lane = tid & 63, l4 = lane >> 4, lm = lane & 15;
    int jj = 127 - (blockIdx.x >> 2);            // q-tile (16 rows), heavy-first
    int bh = ((blockIdx.x & 3) << 2) + w;        // 0..15
    int b = bh >> 3, h = bh & 7;
    int q0 = jj * 16;
    int qmax = q0 + 15;
    char* pb = pls[w];

    // Q fragments: lane holds Q[q0+lm][df*32 + l4*8 .. +8]
    const unsigned short* qg = qb + ((size_t)bh * Sn + q0 + lm) * HDn;
    bf16x8 qf[4];
    #pragma unroll
    for (int df = 0; df < 4; ++df)
        qf[df] = *(const bf16x8*)(qg + df * 32 + l4 * 8);

    f32x4 acc[8];
    #pragma unroll
    for (int dg = 0; dg < 8; ++dg) acc[dg] = (f32x4){0.f,0.f,0.f,0.f};
    float mrun[4] = {-1e30f,-1e30f,-1e30f,-1e30f};
    float lrun[4] = {0.f,0.f,0.f,0.f};

    const float scale = 0.08838834764831845f;
    const unsigned short* kg = kb + (size_t)bh * Sn * HDn;       // [s][d]
    const unsigned short* vg = vtb + (size_t)bh * HDn * Sn;      // [d][s]
    int ntiles = (qmax >> 6) + 1;

    for (int t = 0; t < ntiles; ++t){
        // ---- scores: consecutive-key mapping, col c of mfma kc <-> key 64t+4c+kc
        f32x4 sf[4];
        #pragma unroll
        for (int kc = 0; kc < 4; ++kc) sf[kc] = (f32x4){0.f,0.f,0.f,0.f};
        #pragma unroll
        for (int kc = 0; kc < 4; ++kc){
            const unsigned short* kr = kg + (size_t)(64 * t + 4 * lm + kc) * HDn + l4 * 8;
            #pragma unroll
            for (int df = 0; df < 4; ++df){
                bf16x8 kf = *(const bf16x8*)(kr + df * 32);
                sf[kc] = __builtin_amdgcn_mfma_f32_16x16x32_bf16(qf[df], kf, sf[kc], 0, 0, 0);
            }
        }
        bool needmask = (64 * t + 63 > qmax);
        float cr[4];
        #pragma unroll
        for (int r = 0; r < 4; ++r){
            float s0v = sf[0][r] * scale, s1v = sf[1][r] * scale,
                  s2v = sf[2][r] * scale, s3v = sf[3][r] * scale;
            if (needmask){
                int qr = q0 + 4 * l4 + r;
                int j0k = 64 * t + 4 * lm;
                s0v = (j0k     > qr) ? -1e30f : s0v;
                s1v = (j0k + 1 > qr) ? -1e30f : s1v;
                s2v = (j0k + 2 > qr) ? -1e30f : s2v;
                s3v = (j0k + 3 > qr) ? -1e30f : s3v;
            }
            float mx = fmaxf(fmaxf(s0v, s1v), fmaxf(s2v, s3v));
            #pragma unroll
            for (int o = 8; o >= 1; o >>= 1) mx = fmaxf(mx, __shfl_xor(mx, o));
            float mnew = fmaxf(mrun[r], mx);
            float c = __expf(mrun[r] - mnew);
            float p0 = __expf(s0v - mnew), p1 = __expf(s1v - mnew),
                  p2 = __expf(s2v - mnew), p3 = __expf(s3v - mnew);
            float ps = p0 + p1 + p2 + p3;
            #pragma unroll
            for (int o = 8; o >= 1; o >>= 1) ps += __shfl_xor(ps, o);
            lrun[r] = lrun[r] * c + ps;
            mrun[r] = mnew;
            cr[r] = c;
            int prow = 4 * l4 + r;
            uint2 pkd = {pk2(p0, p1), pk2(p2, p3)};
            *(uint2*)(pb + prow * 128 + ((lm * 8) ^ ((prow & 7) << 4))) = pkd;
        }
        #pragma unroll
        for (int dg = 0; dg < 8; ++dg){
            acc[dg][0] *= cr[0]; acc[dg][1] *= cr[1];
            acc[dg][2] *= cr[2]; acc[dg][3] *= cr[3];
        }
        // ---- PV: A = P (per-wave LDS), B = V^T rows (direct global)
        #pragma unroll
        for (int ks = 0; ks < 2; ++ks){
            bf16x8 pa = *(const bf16x8*)(pb + lm * 128 + ((ks * 64 + l4 * 16) ^ ((lm & 7) << 4)));
            #pragma unroll
            for (int dg = 0; dg < 8; ++dg){
                const unsigned short* vr = vg + (size_t)(16 * dg + lm) * Sn + 64 * t + ks * 32 + l4 * 8;
                bf16x8 vf = *(const bf16x8*)vr;
                acc[dg] = __builtin_amdgcn_mfma_f32_16x16x32_bf16(pa, vf, acc[dg], 0, 0, 0);
            }
        }
    }
    // ---- epilogue: complete rows, direct bf16 y write
    #pragma unroll
    for (int r = 0; r < 4; ++r){
        float inv = 1.f / lrun[r];
        int row = q0 + 4 * l4 + r;
        unsigned short* yr = ybf + ((size_t)b * Sn + row) * Dn + h * HDn;
        #pragma unroll
        for (int dg = 0; dg < 8; ++dg)
            yr[16 * dg + lm] = f2bf(acc[dg][r] * inv);
    }
}

extern "C" void kernel_launch(void* const* d_in, const int* in_sizes, int n_in,
                              void* d_out, int out_size, void* d_ws, size_t ws_size,
                              hipStream_t stream){
    const float* x      = (const float*)d_in[0];
    const float* A      = (const float*)d_in[1];
    const float* Bm     = (const float*)d_in[2];
    const float* C_q    = (const float*)d_in[3];
    const float* C_k    = (const float*)d_in[4];
    const float* C_v    = (const float*)d_in[5];
    const float* C_o    = (const float*)d_in[6];
    const float* C_fc   = (const float*)d_in[7];
    const float* C_proj = (const float*)d_in[8];
    const float* scale1 = (const float*)d_in[9];
    const float* scale2 = (const float*)d_in[10];
    float* out = (float*)d_out;

    char* ws = (char*)d_ws;
    size_t off = 0;
    auto alloc = [&](size_t bytes)->char*{ char* p = ws + off; off += (bytes + 255) & ~(size_t)255; return p; };
    unsigned short* qb   = (unsigned short*)alloc((size_t)Mn * Dn * 2);   // 8MB
    unsigned short* kb   = (unsigned short*)alloc((size_t)Mn * Dn * 2);   // 8MB
    unsigned short* vtb  = (unsigned short*)alloc((size_t)Mn * Dn * 2);   // 8MB
    unsigned short* ybf  = (unsigned short*)alloc((size_t)Mn * Dn * 2);   // 8MB
    float*          tp   = (float*)alloc(4 * TSTRIDE * 4);                // 4MB
    float*          ssp  = (float*)alloc(4 * (size_t)Mn * 4);             // 64KB
    unsigned short* At0  = (unsigned short*)alloc(65536 * 2);
    unsigned short* At1  = (unsigned short*)alloc(65536 * 2);
    unsigned short* At2  = (unsigned short*)alloc(65536 * 2);
    unsigned short* Btq  = (unsigned short*)alloc(65536 * 2);
    unsigned short* Btk  = (unsigned short*)alloc(65536 * 2);
    unsigned short* Btv  = (unsigned short*)alloc(65536 * 2);
    unsigned short* Bto  = (unsigned short*)alloc(65536 * 2);
    unsigned short* Btfc = (unsigned short*)alloc(65536 * 2);
    unsigned short* Btpr = (unsigned short*)alloc(65536 * 2);
    float2*         rt   = (float2*)alloc((size_t)Sn * 64 * 8);           // 1MB
    unsigned short* mb   = kb;  // overlay: kb dead after attention

    prep_g<<<2816, 256, 0, stream>>>(A, Bm, C_q, C_k, C_v, C_o, C_fc, C_proj,
                                     scale1, scale2, At0, At1, At2,
                                     Btq, Btk, Btv, Bto, Btfc, Btpr, rt);
    // t1 partials = x @ At1 (s1 folded), ss = rowwise sumsq(x)
    down_g<0, 1><<<dim3(Mn / 64, 4), 256, 0, stream>>>(x, At1, tp, ssp);
    // q,k (roped) row-major; v^T ; rms fused in staging
    qkv_g<<<dim3(Mn / 64, 4), 256, 0, stream>>>(tp, ssp, Btq, Btk, Btv, rt, qb, kb, vtb);
    // barrier-free per-wave flash attention -> ybf
    attn3_kernel<<<512, 256, 0, stream>>>(qb, kb, vtb, ybf);
    // t2 partials = y @ At0
    down_g<1, 0><<<dim3(Mn / 64, 4), 256, 0, stream>>>(ybf, At0, tp, nullptr);
    // x1 = x + t2 @ Bto
    up_g<0, 1, 0, 0><<<dim3(Mn / 32, 4), 256, 0, stream>>>(tp, nullptr, Bto, x, out);
    // t3 partials = x1 @ At2 (s2 folded), ss = sumsq(x1)
    down_g<0, 1><<<dim3(Mn / 64, 4), 256, 0, stream>>>(out, At2, tp, ssp);
    // mb = silu(rms-scaled t3 @ Btfc) (bf16)
    up_g<1, 0, 1, 1><<<dim3(Mn / 32, 4), 256, 0, stream>>>(tp, ssp, Btfc, nullptr, mb);
    // t4 partials = mb @ At0
    down_g<1, 0><<<dim3(Mn / 64, 4), 256, 0, stream>>>(mb, At0, tp, nullptr);
    // out = x1 + t4 @ Btpr
    up_g<0, 1, 0, 0><<<dim3(Mn / 32, 4), 256, 0, stream>>>(tp, nullptr, Btpr, out, out);
}

// Round 9
// 165.017 us; speedup vs baseline: 1.7908x; 1.7908x over previous
//
#include <hip/hip_runtime.h>

// HolographicBlock: B=2, S=2048, D=1024, R=64, H=8, HD=128
// Projections = bf16 MFMA GEMMs (K-split down-proj, f32 partials).
// Attention = R5 grid (384 blocks, dbuf 80KB LDS, reg-prefetch) +
// permuted K-image (packed P stores) + STATIC-OFFSET softmax (p=exp(s-8),
// no online max, no rescale, no per-iter cross-lane reduction).

#define Bn 2
#define Sn 2048
#define Dn 1024
#define Rn 64
#define Hn 8
#define HDn 128
#define Mn (Bn*Sn)   // 4096 rows
#define TSTRIDE ((size_t)Mn * Rn)

typedef __bf16 bf16x8 __attribute__((ext_vector_type(8)));
typedef float f32x4 __attribute__((ext_vector_type(4)));

__device__ __forceinline__ float bf2f(unsigned short u){
    union { unsigned int i; float f; } x; x.i = ((unsigned int)u) << 16; return x.f;
}
__device__ __forceinline__ unsigned short f2bf(float f){
    union { float f; unsigned int i; } x; x.f = f;
    unsigned int r = x.i + 0x7fffu + ((x.i >> 16) & 1u);
    return (unsigned short)(r >> 16);
}
__device__ __forceinline__ unsigned int pk2(float a, float b){
    return (unsigned int)f2bf(a) | ((unsigned int)f2bf(b) << 16);
}

// ---------------- prep: bf16 transposed weights + rope table
__global__ __launch_bounds__(256) void prep_g(const float* __restrict__ A,
                                              const float* __restrict__ Bsrc,
                                              const float* __restrict__ Cq, const float* __restrict__ Ck,
                                              const float* __restrict__ Cv, const float* __restrict__ Co,
                                              const float* __restrict__ Cfc, const float* __restrict__ Cpr,
                                              const float* __restrict__ s1, const float* __restrict__ s2,
                                              unsigned short* __restrict__ At0, unsigned short* __restrict__ At1,
                                              unsigned short* __restrict__ At2,
                                              unsigned short* __restrict__ Btq, unsigned short* __restrict__ Btk,
                                              unsigned short* __restrict__ Btv, unsigned short* __restrict__ Bto,
                                              unsigned short* __restrict__ Btfc, unsigned short* __restrict__ Btpr,
                                              float2* __restrict__ rt){
    int idx = blockIdx.x * 256 + threadIdx.x;
    if (idx < 3 * 65536){
        int v = idx >> 16, e = idx & 65535;
        int r = e >> 10, d = e & 1023;
        float sc = (v == 0) ? 1.f : (v == 1 ? s1[d] : s2[d]);
        unsigned short val = f2bf(A[d * 64 + r] * sc);
        (v == 0 ? At0 : v == 1 ? At1 : At2)[e] = val;
    } else if (idx < 9 * 65536){
        int v = (idx - 3 * 65536) >> 16, e = idx & 65535;
        int d = e >> 6, r = e & 63;
        const float* C = v==0?Cq : v==1?Ck : v==2?Cv : v==3?Co : v==4?Cfc : Cpr;
        unsigned short val = f2bf(Bsrc[r * 1024 + d] * C[r]);
        (v==0?Btq : v==1?Btk : v==2?Btv : v==3?Bto : v==4?Btfc : Btpr)[e] = val;
    } else if (idx < 9 * 65536 + Sn * 64){
        int e = idx - 9 * 65536;
        int s = e >> 6, f = e & 63;
        float inv = exp2f(-(float)f * (13.287712379549449f / 64.0f));
        float fr = (float)s * inv;
        float sn, cs; sincosf(fr, &sn, &cs);
        rt[e] = make_float2(cs, sn);
    }
}

// ---------------- down GEMM (K-split): tpart[sp][m][r] = sum_{d in split} in[m][d] * At[r][d]
template<int IN_BF16, int WRITE_SS>
__global__ __launch_bounds__(256) void down_g(const void* __restrict__ inp,
                                              const unsigned short* __restrict__ At,
                                              float* __restrict__ tpart,
                                              float* __restrict__ sspart){
    __shared__ char xt[8192];
    __shared__ char at[8192];
    int tid = threadIdx.x;
    int m0 = blockIdx.x * 64, sp = blockIdx.y;
    int row = tid >> 2, q4 = tid & 3;
    int w = tid >> 6, lane = tid & 63, l4 = lane >> 4, lm = lane & 15;
    int swz = (row & 7) << 4;
    float ss = 0.f;
    f32x4 acc[4];
    #pragma unroll
    for (int nt = 0; nt < 4; ++nt) acc[nt] = (f32x4){0.f,0.f,0.f,0.f};

    float4 xr[4]; uint4 xrb[2]; uint4 ar[2];
    #define LOADC(c) { int k0 = sp * 256 + (c) * 64; \
        if (!IN_BF16){ const float4* s = (const float4*)((const float*)inp + (size_t)(m0+row)*1024 + k0 + q4*16); \
            xr[0]=s[0]; xr[1]=s[1]; xr[2]=s[2]; xr[3]=s[3]; } \
        else { const uint4* s = (const uint4*)((const unsigned short*)inp + (size_t)(m0+row)*1024 + k0 + q4*16); \
            xrb[0]=s[0]; xrb[1]=s[1]; } \
        const uint4* a = (const uint4*)(At + (size_t)row*1024 + k0 + q4*16); \
        ar[0]=a[0]; ar[1]=a[1]; }

    LOADC(0);
    for (int c = 0; c < 4; ++c){
        int b0 = row * 128 + ((q4 * 32) ^ swz);
        int b1 = row * 128 + ((q4 * 32 + 16) ^ swz);
        if (!IN_BF16){
            if (WRITE_SS){
                #pragma unroll
                for (int i = 0; i < 4; ++i)
                    ss += xr[i].x*xr[i].x + xr[i].y*xr[i].y + xr[i].z*xr[i].z + xr[i].w*xr[i].w;
            }
            uint4 p0 = {pk2(xr[0].x,xr[0].y), pk2(xr[0].z,xr[0].w), pk2(xr[1].x,xr[1].y), pk2(xr[1].z,xr[1].w)};
            uint4 p1 = {pk2(xr[2].x,xr[2].y), pk2(xr[2].z,xr[2].w), pk2(xr[3].x,xr[3].y), pk2(xr[3].z,xr[3].w)};
            *(uint4*)(xt + b0) = p0; *(uint4*)(xt + b1) = p1;
        } else {
            *(uint4*)(xt + b0) = xrb[0]; *(uint4*)(xt + b1) = xrb[1];
        }
        *(uint4*)(at + b0) = ar[0]; *(uint4*)(at + b1) = ar[1];
        __syncthreads();
        if (c < 3) LOADC(c + 1);
        #pragma unroll
        for (int ks = 0; ks < 2; ++ks){
            int arow = 16 * w + lm;
            bf16x8 af = *(const bf16x8*)(xt + arow * 128 + ((ks*64 + l4*16) ^ ((arow & 7) << 4)));
            #pragma unroll
            for (int nt = 0; nt < 4; ++nt){
                int brow = nt * 16 + lm;
                bf16x8 bf = *(const bf16x8*)(at + brow * 128 + ((ks*64 + l4*16) ^ ((brow & 7) << 4)));
                acc[nt] = __builtin_amdgcn_mfma_f32_16x16x32_bf16(af, bf, acc[nt], 0, 0, 0);
            }
        }
        __syncthreads();
    }
    #undef LOADC
    if (!IN_BF16 && WRITE_SS){
        ss += __shfl_xor(ss, 1); ss += __shfl_xor(ss, 2);
        if (q4 == 0) sspart[sp * Mn + m0 + row] = ss;
    }
    #pragma unroll
    for (int nt = 0; nt < 4; ++nt)
        #pragma unroll
        for (int r = 0; r < 4; ++r){
            int ml = 16 * w + 4 * l4 + r;
            tpart[(size_t)sp * TSTRIDE + (size_t)(m0 + ml) * 64 + nt * 16 + lm] = acc[nt][r];
        }
}

// ---------------- stage t tile (sum 4 K-split partials, optional rms scale) into swizzled LDS
template<int DORMS>
__device__ __forceinline__ void stage_t(char* tt, const float* __restrict__ tpart,
                                        const float* __restrict__ sspart, int m0, int tid){
    int row = tid >> 2, q4 = tid & 3;
    const float* bp = tpart + (size_t)(m0 + row) * 64 + q4 * 16;
    float4 s[4];
    #pragma unroll
    for (int i = 0; i < 4; ++i){
        float4 a = ((const float4*)(bp + 0 * TSTRIDE))[i];
        float4 b = ((const float4*)(bp + 1 * TSTRIDE))[i];
        float4 c = ((const float4*)(bp + 2 * TSTRIDE))[i];
        float4 d = ((const float4*)(bp + 3 * TSTRIDE))[i];
        s[i] = make_float4(a.x+b.x+c.x+d.x, a.y+b.y+c.y+d.y, a.z+b.z+c.z+d.z, a.w+b.w+c.w+d.w);
    }
    float rr = 1.f;
    if (DORMS){
        int m = m0 + row;
        float ssum = sspart[m] + sspart[Mn + m] + sspart[2*Mn + m] + sspart[3*Mn + m];
        rr = rsqrtf(ssum * (1.f / 1024.f) + 1.1920929e-07f);
    }
    #pragma unroll
    for (int i = 0; i < 4; ++i){ s[i].x*=rr; s[i].y*=rr; s[i].z*=rr; s[i].w*=rr; }
    int swz = (row & 7) << 4;
    uint4 p0 = {pk2(s[0].x,s[0].y), pk2(s[0].z,s[0].w), pk2(s[1].x,s[1].y), pk2(s[1].z,s[1].w)};
    uint4 p1 = {pk2(s[2].x,s[2].y), pk2(s[2].z,s[2].w), pk2(s[3].x,s[3].y), pk2(s[3].z,s[3].w)};
    *(uint4*)(tt + row * 128 + ((q4 * 32) ^ swz)) = p0;
    *(uint4*)(tt + row * 128 + ((q4 * 32 + 16) ^ swz)) = p1;
}

// ---------------- up GEMM: M-tile 32 x N-chunk 256, K=64
template<int SILU, int HASBASE, int OUT_BF16, int DORMS>
__global__ __launch_bounds__(256) void up_g(const float* __restrict__ tpart,
                                            const float* __restrict__ sspart,
                                            const unsigned short* __restrict__ Bt,
                                            const float* base,
                                            void* __restrict__ outp){
    __shared__ char tt[4096];
    __shared__ char bb[32768];
    int tid = threadIdx.x;
    int m0 = blockIdx.x * 32, n0 = blockIdx.y * 256;
    int w = tid >> 6, lane = tid & 63, l4 = lane >> 4, lm = lane & 15;
    int wm = w & 1, wn = w >> 1;
    if (tid < 128) stage_t<DORMS>(tt, tpart, sspart, m0, tid);
    {
        const uint4* s = (const uint4*)(Bt + (size_t)(n0 + tid) * 64);
        #pragma unroll
        for (int j = 0; j < 8; ++j){
            uint4 v = s[j];
            *(uint4*)(bb + tid * 128 + ((j * 16) ^ ((tid & 7) << 4))) = v;
        }
    }
    __syncthreads();
    bf16x8 af[2];
    #pragma unroll
    for (int ks = 0; ks < 2; ++ks){
        int arow = 16 * wm + lm;
        af[ks] = *(const bf16x8*)(tt + arow * 128 + ((ks*64 + l4*16) ^ ((arow & 7) << 4)));
    }
    f32x4 acc[8];
    #pragma unroll
    for (int nt = 0; nt < 8; ++nt) acc[nt] = (f32x4){0.f,0.f,0.f,0.f};
    #pragma unroll
    for (int nt = 0; nt < 8; ++nt){
        int brow = wn * 128 + nt * 16 + lm;
        #pragma unroll
        for (int ks = 0; ks < 2; ++ks){
            bf16x8 bf = *(const bf16x8*)(bb + brow * 128 + ((ks*64 + l4*16) ^ ((brow & 7) << 4)));
            acc[nt] = __builtin_amdgcn_mfma_f32_16x16x32_bf16(af[ks], bf, acc[nt], 0, 0, 0);
        }
    }
    #pragma unroll
    for (int nt = 0; nt < 8; ++nt)
        #pragma unroll
        for (int r = 0; r < 4; ++r){
            int m = m0 + 16 * wm + 4 * l4 + r;
            int n = n0 + wn * 128 + nt * 16 + lm;
            float v = acc[nt][r];
            if (SILU) v = v / (1.f + __expf(-v));
            if (HASBASE) v += base[(size_t)m * 1024 + n];
            if (OUT_BF16) ((unsigned short*)outp)[(size_t)m * 1024 + n] = f2bf(v);
            else          ((float*)outp)[(size_t)m * 1024 + n] = v;
        }
}

// ---------------- fused QKV up-proj + RoPE; K,V written as pre-swizzled tile images
// Kimg: [bh][tile32][imgrow64][256B swz], imgrow rho(t)=16*(t&3)+(t>>2) holds key t;
// Vimg: [bh][tile32][d128][128B swz] (natural key order in columns)
__global__ __launch_bounds__(256) void qkv_g(const float* __restrict__ tpart,
                                             const float* __restrict__ sspart,
                                             const unsigned short* __restrict__ Btq,
                                             const unsigned short* __restrict__ Btk,
                                             const unsigned short* __restrict__ Btv,
                                             const float2* __restrict__ rt,
                                             unsigned short* __restrict__ qout,
                                             char* __restrict__ Kimg,
                                             char* __restrict__ Vimg){
    __shared__ char tt[8192];
    __shared__ char bb[32768];
    int tid = threadIdx.x;
    int m0 = blockIdx.x * 64, n0 = blockIdx.y * 256;
    int b = m0 >> 11, s0 = m0 & (Sn - 1);
    int h0 = n0 >> 7;
    int w = tid >> 6, lane = tid & 63, l4 = lane >> 4, lm = lane & 15;
    stage_t<1>(tt, tpart, sspart, m0, tid);
    #define STAGE_B(SRC) { const uint4* s = (const uint4*)((SRC) + (size_t)(n0 + tid) * 64); \
        _Pragma("unroll") for (int j = 0; j < 8; ++j){ uint4 v = s[j]; \
            *(uint4*)(bb + tid * 128 + ((j * 16) ^ ((tid & 7) << 4))) = v; } }
    STAGE_B(Btq);
    __syncthreads();
    bf16x8 af[2];
    #pragma unroll
    for (int ks = 0; ks < 2; ++ks){
        int arow = 16 * w + lm;
        af[ks] = *(const bf16x8*)(tt + arow * 128 + ((ks*64 + l4*16) ^ ((arow & 7) << 4)));
    }
    f32x4 acc[16];
    float2 cs[4][4];
    #pragma unroll
    for (int ntb = 0; ntb < 4; ++ntb)
        #pragma unroll
        for (int r = 0; r < 4; ++r)
            cs[ntb][r] = rt[(size_t)(s0 + 16*w + 4*l4 + r) * 64 + ntb * 16 + lm];

    #define MMUL() { _Pragma("unroll") for (int nt = 0; nt < 16; ++nt) acc[nt] = (f32x4){0.f,0.f,0.f,0.f}; \
        _Pragma("unroll") for (int nt = 0; nt < 16; ++nt){ int brow = nt * 16 + lm; \
            _Pragma("unroll") for (int ks = 0; ks < 2; ++ks){ \
                bf16x8 bf = *(const bf16x8*)(bb + brow * 128 + ((ks*64 + l4*16) ^ ((brow & 7) << 4))); \
                acc[nt] = __builtin_amdgcn_mfma_f32_16x16x32_bf16(af[ks], bf, acc[nt], 0, 0, 0); } } }

    #define ROPE() { _Pragma("unroll") for (int g = 0; g < 2; ++g) \
        _Pragma("unroll") for (int ntb = 0; ntb < 4; ++ntb){ int lo = g*8 + ntb, hi = lo + 4; \
            _Pragma("unroll") for (int r = 0; r < 4; ++r){ float2 c = cs[ntb][r]; \
                float a = acc[lo][r], bq = acc[hi][r]; \
                acc[lo][r] = a * c.x + bq * c.y; acc[hi][r] = -a * c.y + bq * c.x; } } }

    #define BOUNCE() { \
        _Pragma("unroll") for (int nt = 0; nt < 16; ++nt) \
            _Pragma("unroll") for (int r = 0; r < 4; ++r){ \
                int nl = nt * 16 + lm, ml2 = 16 * w + 4 * l4 + r; \
                *(unsigned short*)(bb + ml2 * 512 + ((nl * 2) ^ ((ml2 & 7) << 4))) = f2bf(acc[nt][r]); } \
        __syncthreads(); }

    // ---- Q -> [bh,s,hd]
    MMUL(); ROPE();
    __syncthreads();
    BOUNCE();
    {
        int ml = tid >> 2, seg = tid & 3;
        int head = h0 + (seg >> 1), hd0q = (seg & 1) * 64;
        size_t dstbase = (((size_t)(b * 8 + head) * Sn + (s0 + ml)) * 128 + hd0q);
        #pragma unroll
        for (int j = 0; j < 8; ++j){
            uint4 v = *(const uint4*)(bb + ml * 512 + ((seg * 128 + j * 16) ^ ((ml & 7) << 4)));
            *(uint4*)(qout + dstbase + j * 8) = v;
        }
    }
    __syncthreads();
    // ---- K -> swizzled tile image, permuted rows (image row rho(ml) holds key s0+ml)
    STAGE_B(Btk);
    __syncthreads();
    MMUL(); ROPE();
    __syncthreads();
    BOUNCE();
    {
        int ml = tid >> 2, seg = tid & 3;
        int hd0q = (seg & 1) * 64;
        int head = h0 + (seg >> 1);
        int pr = 16 * (ml & 3) + (ml >> 2);   // permuted image row
        size_t rowb = (((size_t)(b * 8 + head) * 32 + (s0 >> 6)) * 64 + pr) * 256;
        #pragma unroll
        for (int j = 0; j < 8; ++j){
            uint4 v = *(const uint4*)(bb + ml * 512 + ((seg * 128 + j * 16) ^ ((ml & 7) << 4)));
            int cb = hd0q * 2 + j * 16;
            *(uint4*)(Kimg + rowb + (cb ^ ((pr & 7) << 4))) = v;
        }
    }
    __syncthreads();
    // ---- V -> transposed swizzled tile image (natural key order)
    STAGE_B(Btv);
    __syncthreads();
    MMUL();
    __syncthreads();
    #pragma unroll
    for (int nt = 0; nt < 16; ++nt)
        #pragma unroll
        for (int r = 0; r < 4; ++r){
            int nl = nt * 16 + lm, ml2 = 16 * w + 4 * l4 + r;
            *(unsigned short*)(bb + nl * 128 + ((ml2 * 2) ^ ((nl & 7) << 4))) = f2bf(acc[nt][r]);
        }
    __syncthreads();
    {
        int head = h0 + (tid >> 7), d = tid & 127;
        size_t rowb = (((size_t)(b * 8 + head) * 32 + (s0 >> 6)) * 128 + d) * 128;
        #pragma unroll
        for (int j = 0; j < 8; ++j){
            uint4 v = *(const uint4*)(bb + tid * 128 + ((j * 16) ^ ((tid & 7) << 4)));
            *(uint4*)(Vimg + rowb + ((j * 16) ^ ((d & 7) << 4))) = v;
        }
    }
    #undef STAGE_B
    #undef MMUL
    #undef ROPE
    #undef BOUNCE
}

// ---------------- K-split flash attention: static-offset softmax p=exp(s-8)
// 384 blocks: grp0: (J=8+g, slice0, 16 tiles); grp1: (J=15-g, slice1, 2J-14 tiles);
// grp2: (J=7-g, direct, 2J+2 tiles). 4 waves, 32 q-rows/wave. dbuf 80KB LDS.
__global__ __launch_bounds__(256, 2) void attn2_kernel(const unsigned short* __restrict__ qb,
                                                       const char* __restrict__ Kimg,
                                                       const char* __restrict__ Vimg,
                                                       unsigned short* __restrict__ ybf,
                                                       float* __restrict__ pacc,
                                                       float* __restrict__ pl){
    __shared__ uint4 smem4[81920 / 16];
    char* smem = (char*)smem4;
    int tid = threadIdx.x;
    int w = tid >> 6, lane = tid & 63, l4 = lane >> 4, lm = lane & 15;
    int id = blockIdx.x;
    int grp = id >> 7, wi = id & 127;
    int bh = wi & 15, g = wi >> 4;
    int J, t0, niters, direct, slice;
    if (grp == 0){ J = 8 + g;  t0 = 0;  niters = 16;         direct = 0; slice = (bh * 8 + g) * 2; }
    else if (grp == 1){ J = 15 - g; t0 = 16; niters = 2 * J - 14; direct = 0; slice = (bh * 8 + (J - 8)) * 2 + 1; }
    else { J = 7 - g;  t0 = 0;  niters = 2 * J + 2;  direct = 1; slice = 0; }
    int b = bh >> 3, h = bh & 7;
    int qrow0w = 128 * J + 32 * w;
    int wqmax = qrow0w + 31;

    bf16x8 qf[2][4];
    #pragma unroll
    for (int f = 0; f < 2; ++f){
        const unsigned short* qg = qb + ((size_t)bh * Sn + qrow0w + 16 * f + lm) * HDn;
        #pragma unroll
        for (int df = 0; df < 4; ++df)
            qf[f][df] = *(const bf16x8*)(qg + df * 32 + l4 * 8);
    }
    f32x4 acc[2][8];
    #pragma unroll
    for (int f = 0; f < 2; ++f)
        #pragma unroll
        for (int dg = 0; dg < 8; ++dg) acc[f][dg] = (f32x4){0.f,0.f,0.f,0.f};
    float lp[2][4];
    #pragma unroll
    for (int f = 0; f < 2; ++f)
        #pragma unroll
        for (int r = 0; r < 4; ++r) lp[f][r] = 0.f;

    const float scale = 0.08838834764831845f;
    size_t imgbase = (size_t)bh * 32 * 16384;

    uint4 sk[4], sv4[4];
    {   // prologue: stage t0 -> buf0
        size_t tb = imgbase + (size_t)t0 * 16384;
        #pragma unroll
        for (int i = 0; i < 4; ++i){
            sk[i]  = *(const uint4*)(Kimg + tb + i * 4096 + tid * 16);
            sv4[i] = *(const uint4*)(Vimg + tb + i * 4096 + tid * 16);
        }
        #pragma unroll
        for (int i = 0; i < 4; ++i){
            *(uint4*)(smem + i * 4096 + tid * 16) = sk[i];
            *(uint4*)(smem + 16384 + i * 4096 + tid * 16) = sv4[i];
        }
    }
    __syncthreads();

    for (int it = 0; it < niters; ++it){
        int t = t0 + it;
        int bsel = (it & 1) << 15;
        if (it + 1 < niters){
            size_t tb = imgbase + (size_t)(t + 1) * 16384;
            #pragma unroll
            for (int i = 0; i < 4; ++i){
                sk[i]  = *(const uint4*)(Kimg + tb + i * 4096 + tid * 16);
                sv4[i] = *(const uint4*)(Vimg + tb + i * 4096 + tid * 16);
            }
        }
        if (64 * t <= wqmax){
            char* KL = smem + bsel;
            char* VL = smem + bsel + 16384;
            char* pb = smem + 65536 + (w << 12);
            f32x4 sf[2][4];
            #pragma unroll
            for (int kc = 0; kc < 4; ++kc){ sf[0][kc] = (f32x4){0.f,0.f,0.f,0.f}; sf[1][kc] = (f32x4){0.f,0.f,0.f,0.f}; }
            #pragma unroll
            for (int kc = 0; kc < 4; ++kc){
                int krow = 16 * kc + lm;
                int ksw = (krow & 7) << 4;
                #pragma unroll
                for (int df = 0; df < 4; ++df){
                    bf16x8 kf = *(const bf16x8*)(KL + krow * 256 + ((df * 64 + l4 * 16) ^ ksw));
                    sf[0][kc] = __builtin_amdgcn_mfma_f32_16x16x32_bf16(qf[0][df], kf, sf[0][kc], 0, 0, 0);
                    sf[1][kc] = __builtin_amdgcn_mfma_f32_16x16x32_bf16(qf[1][df], kf, sf[1][kc], 0, 0, 0);
                }
            }
            // lane's score sf[kc][r] is for TRUE key 64t + 4*lm + kc (permuted image)
            bool needmask = (64 * t + 63 > qrow0w);
            #pragma unroll
            for (int f = 0; f < 2; ++f){
                #pragma unroll
                for (int r = 0; r < 4; ++r){
                    float s0v = sf[f][0][r] * scale, s1v = sf[f][1][r] * scale,
                          s2v = sf[f][2][r] * scale, s3v = sf[f][3][r] * scale;
                    if (needmask){
                        int qr = qrow0w + 16 * f + 4 * l4 + r;
                        int j0k = 64 * t + 4 * lm;
                        s0v = (j0k     > qr) ? -1e30f : s0v;
                        s1v = (j0k + 1 > qr) ? -1e30f : s1v;
                        s2v = (j0k + 2 > qr) ? -1e30f : s2v;
                        s3v = (j0k + 3 > qr) ? -1e30f : s3v;
                    }
                    // static-offset softmax: exact, no running max needed
                    float p0 = __expf(s0v - 8.f), p1 = __expf(s1v - 8.f),
                          p2 = __expf(s2v - 8.f), p3 = __expf(s3v - 8.f);
                    lp[f][r] += p0 + p1 + p2 + p3;
                    int prow = 16 * f + 4 * l4 + r;
                    uint2 pkd = {pk2(p0, p1), pk2(p2, p3)};
                    *(uint2*)(pb + prow * 128 + ((lm * 8) ^ ((prow & 7) << 4))) = pkd;
                }
            }
            #pragma unroll
            for (int ks = 0; ks < 2; ++ks){
                int pcol = (ks * 64 + l4 * 16) ^ ((lm & 7) << 4);
                bf16x8 pa0 = *(const bf16x8*)(pb + lm * 128 + pcol);
                bf16x8 pa1 = *(const bf16x8*)(pb + (16 + lm) * 128 + pcol);
                #pragma unroll
                for (int dg = 0; dg < 8; ++dg){
                    int vrow = 16 * dg + lm;
                    bf16x8 vf = *(const bf16x8*)(VL + vrow * 128 + ((ks * 64 + l4 * 16) ^ ((vrow & 7) << 4)));
                    acc[0][dg] = __builtin_amdgcn_mfma_f32_16x16x32_bf16(pa0, vf, acc[0][dg], 0, 0, 0);
                    acc[1][dg] = __builtin_amdgcn_mfma_f32_16x16x32_bf16(pa1, vf, acc[1][dg], 0, 0, 0);
                }
            }
        }
        if (it + 1 < niters){
            int ob = bsel ^ 32768;
            #pragma unroll
            for (int i = 0; i < 4; ++i){
                *(uint4*)(smem + ob + i * 4096 + tid * 16) = sk[i];
                *(uint4*)(smem + ob + 16384 + i * 4096 + tid * 16) = sv4[i];
            }
        }
        __syncthreads();
    }
    // epilogue: one cross-lane reduce of l per row (deferred from the loop)
    float lsum[2][4];
    #pragma unroll
    for (int f = 0; f < 2; ++f)
        #pragma unroll
        for (int r = 0; r < 4; ++r){
            float l_ = lp[f][r];
            l_ += __shfl_xor(l_, 1);
            l_ += __shfl_xor(l_, 2);
            l_ += __shfl_xor(l_, 4);
            l_ += __shfl_xor(l_, 8);
            lsum[f][r] = l_;
        }
    if (direct){
        #pragma unroll
        for (int f = 0; f < 2; ++f)
            #pragma unroll
            for (int r = 0; r < 4; ++r){
                float inv = 1.f / lsum[f][r];
                int row = qrow0w + 16 * f + 4 * l4 + r;
                unsigned short* yr = ybf + ((size_t)b * Sn + row) * Dn + h * HDn;
                #pragma unroll
                for (int dg = 0; dg < 8; ++dg)
                    yr[16 * dg + lm] = f2bf(acc[f][dg][r] * inv);
            }
    } else {
        float* pa_ = pacc + (size_t)slice * 16384;
        #pragma unroll
        for (int f = 0; f < 2; ++f)
            #pragma unroll
            for (int r = 0; r < 4; ++r){
                int row = 32 * w + 16 * f + 4 * l4 + r;
                #pragma unroll
                for (int dg = 0; dg < 8; ++dg)
                    pa_[row * 128 + 16 * dg + lm] = acc[f][dg][r];
                if (lm == 0)
                    pl[slice * 128 + row] = lsum[f][r];
            }
    }
}

// ---------------- combine two K-slices -> y (bf16): O = (A0+A1)/(l0+l1)
__global__ __launch_bounds__(256) void comb_g(const float* __restrict__ pacc,
                                              const float* __restrict__ pl,
                                              unsigned short* __restrict__ ybf){
    int bh = blockIdx.x >> 3, g = blockIdx.x & 7, J = 8 + g;
    int s0 = (bh * 8 + g) * 2, s1 = s0 + 1;
    int tid = threadIdx.x;
    __shared__ float wsum[128];
    if (tid < 128)
        wsum[tid] = 1.f / (pl[s0 * 128 + tid] + pl[s1 * 128 + tid]);
    __syncthreads();
    int b = bh >> 3, h = bh & 7;
    const float4* p0 = (const float4*)(pacc + (size_t)s0 * 16384);
    const float4* p1 = (const float4*)(pacc + (size_t)s1 * 16384);
    #pragma unroll
    for (int i = 0; i < 16; ++i){
        int idx = i * 256 + tid;
        int row = idx >> 5, c4 = idx & 31;
        float4 a0 = p0[idx], a1 = p1[idx];
        float W = wsum[row];
        ushort4 o;
        o.x = f2bf((a0.x + a1.x) * W);
        o.y = f2bf((a0.y + a1.y) * W);
        o.z = f2bf((a0.z + a1.z) * W);
        o.w = f2bf((a0.w + a1.w) * W);
        int srow = 128 * J + row;
        *(ushort4*)(ybf + ((size_t)b * Sn + srow) * Dn + h * HDn + c4 * 4) = o;
    }
}

extern "C" void kernel_launch(void* const* d_in, const int* in_sizes, int n_in,
                              void* d_out, int out_size, void* d_ws, size_t ws_size,
                              hipStream_t stream){
    const float* x      = (const float*)d_in[0];
    const float* A      = (const float*)d_in[1];
    const float* Bm     = (const float*)d_in[2];
    const float* C_q    = (const float*)d_in[3];
    const float* C_k    = (const float*)d_in[4];
    const float* C_v    = (const float*)d_in[5];
    const float* C_o    = (const float*)d_in[6];
    const float* C_fc   = (const float*)d_in[7];
    const float* C_proj = (const float*)d_in[8];
    const float* scale1 = (const float*)d_in[9];
    const float* scale2 = (const float*)d_in[10];
    float* out = (float*)d_out;

    char* ws = (char*)d_ws;
    size_t off = 0;
    auto alloc = [&](size_t bytes)->char*{ char* p = ws + off; off += (bytes + 255) & ~(size_t)255; return p; };
    unsigned short* qb   = (unsigned short*)alloc((size_t)Mn * Dn * 2);   // 8MB
    char*           Kimg = alloc((size_t)16 * 32 * 16384);                // 8MB
    char*           Vimg = alloc((size_t)16 * 32 * 16384);                // 8MB
    unsigned short* ybf  = (unsigned short*)alloc((size_t)Mn * Dn * 2);   // 8MB
    float*          pacc = (float*)alloc((size_t)256 * 16384 * 4);        // 16MB
    float*          pl   = (float*)alloc((size_t)256 * 128 * 4);          // 128KB
    float*          tp   = (float*)alloc(4 * TSTRIDE * 4);                // 4MB
    float*          ssp  = (float*)alloc(4 * (size_t)Mn * 4);             // 64KB
    unsigned short* At0  = (unsigned short*)alloc(65536 * 2);
    unsigned short* At1  = (unsigned short*)alloc(65536 * 2);
    unsigned short* At2  = (unsigned short*)alloc(65536 * 2);
    unsigned short* Btq  = (unsigned short*)alloc(65536 * 2);
    unsigned short* Btk  = (unsigned short*)alloc(65536 * 2);
    unsigned short* Btv  = (unsigned short*)alloc(65536 * 2);
    unsigned short* Bto  = (unsigned short*)alloc(65536 * 2);
    unsigned short* Btfc = (unsigned short*)alloc(65536 * 2);
    unsigned short* Btpr = (unsigned short*)alloc(65536 * 2);
    float2*         rt   = (float2*)alloc((size_t)Sn * 64 * 8);           // 1MB
    unsigned short* mb   = (unsigned short*)Kimg;  // overlay: Kimg dead after attention

    prep_g<<<2816, 256, 0, stream>>>(A, Bm, C_q, C_k, C_v, C_o, C_fc, C_proj,
                                     scale1, scale2, At0, At1, At2,
                                     Btq, Btk, Btv, Bto, Btfc, Btpr, rt);
    down_g<0, 1><<<dim3(Mn / 64, 4), 256, 0, stream>>>(x, At1, tp, ssp);
    qkv_g<<<dim3(Mn / 64, 4), 256, 0, stream>>>(tp, ssp, Btq, Btk, Btv, rt, qb, Kimg, Vimg);
    attn2_kernel<<<384, 256, 0, stream>>>(qb, Kimg, Vimg, ybf, pacc, pl);
    comb_g<<<128, 256, 0, stream>>>(pacc, pl, ybf);
    down_g<1, 0><<<dim3(Mn / 64, 4), 256, 0, stream>>>(ybf, At0, tp, nullptr);
    up_g<0, 1, 0, 0><<<dim3(Mn / 32, 4), 256, 0, stream>>>(tp, nullptr, Bto, x, out);
    down_g<0, 1><<<dim3(Mn / 64, 4), 256, 0, stream>>>(out, At2, tp, ssp);
    up_g<1, 0, 1, 1><<<dim3(Mn / 32, 4), 256, 0, stream>>>(tp, ssp, Btfc, nullptr, mb);
    down_g<1, 0><<<dim3(Mn / 64, 4), 256, 0, stream>>>(mb, At0, tp, nullptr);
    up_g<0, 1, 0, 0><<<dim3(Mn / 32, 4), 256, 0, stream>>>(tp, nullptr, Btpr, out, out);
}

// Round 10
// 161.953 us; speedup vs baseline: 1.8247x; 1.0189x over previous
//
#include <hip/hip_runtime.h>

// HolographicBlock: B=2, S=2048, D=1024, R=64, H=8, HD=128
// Projections = bf16 MFMA GEMMs (K-split down-proj, f32 partials).
// Attention = R9 structure (384 blocks, dbuf 80KB, static-offset softmax) +
// log2e-folded Q scale (v_exp_f32 direct), v_cvt_pk_bf16_f32 packs,
// XCD-aware block remap (bh-pair per XCD -> K/V L2-resident).

#define Bn 2
#define Sn 2048
#define Dn 1024
#define Rn 64
#define Hn 8
#define HDn 128
#define Mn (Bn*Sn)   // 4096 rows
#define TSTRIDE ((size_t)Mn * Rn)

typedef __bf16 bf16x8 __attribute__((ext_vector_type(8)));
typedef float f32x4 __attribute__((ext_vector_type(4)));

__device__ __forceinline__ float bf2f(unsigned short u){
    union { unsigned int i; float f; } x; x.i = ((unsigned int)u) << 16; return x.f;
}
__device__ __forceinline__ unsigned short f2bf(float f){
    union { float f; unsigned int i; } x; x.f = f;
    unsigned int r = x.i + 0x7fffu + ((x.i >> 16) & 1u);
    return (unsigned short)(r >> 16);
}
// packed bf16 pair via HW convert (lo = a, hi = b; RNE)
__device__ __forceinline__ unsigned int pk2(float a, float b){
    unsigned int r;
    asm("v_cvt_pk_bf16_f32 %0, %1, %2" : "=v"(r) : "v"(a), "v"(b));
    return r;
}
// 2^x in one TRANS instruction
__device__ __forceinline__ float vexp2(float x){
    float r;
    asm("v_exp_f32 %0, %1" : "=v"(r) : "v"(x));
    return r;
}

// ---------------- prep: bf16 transposed weights + rope table
// Btq additionally folds attn scale * log2(e) so scores are in exp2 domain.
__global__ __launch_bounds__(256) void prep_g(const float* __restrict__ A,
                                              const float* __restrict__ Bsrc,
                                              const float* __restrict__ Cq, const float* __restrict__ Ck,
                                              const float* __restrict__ Cv, const float* __restrict__ Co,
                                              const float* __restrict__ Cfc, const float* __restrict__ Cpr,
                                              const float* __restrict__ s1, const float* __restrict__ s2,
                                              unsigned short* __restrict__ At0, unsigned short* __restrict__ At1,
                                              unsigned short* __restrict__ At2,
                                              unsigned short* __restrict__ Btq, unsigned short* __restrict__ Btk,
                                              unsigned short* __restrict__ Btv, unsigned short* __restrict__ Bto,
                                              unsigned short* __restrict__ Btfc, unsigned short* __restrict__ Btpr,
                                              float2* __restrict__ rt){
    int idx = blockIdx.x * 256 + threadIdx.x;
    if (idx < 3 * 65536){
        int v = idx >> 16, e = idx & 65535;
        int r = e >> 10, d = e & 1023;
        float sc = (v == 0) ? 1.f : (v == 1 ? s1[d] : s2[d]);
        unsigned short val = f2bf(A[d * 64 + r] * sc);
        (v == 0 ? At0 : v == 1 ? At1 : At2)[e] = val;
    } else if (idx < 9 * 65536){
        int v = (idx - 3 * 65536) >> 16, e = idx & 65535;
        int d = e >> 6, r = e & 63;
        const float* C = v==0?Cq : v==1?Ck : v==2?Cv : v==3?Co : v==4?Cfc : Cpr;
        float extra = (v == 0) ? (0.08838834764831845f * 1.4426950408889634f) : 1.f;
        unsigned short val = f2bf(Bsrc[r * 1024 + d] * C[r] * extra);
        (v==0?Btq : v==1?Btk : v==2?Btv : v==3?Bto : v==4?Btfc : Btpr)[e] = val;
    } else if (idx < 9 * 65536 + Sn * 64){
        int e = idx - 9 * 65536;
        int s = e >> 6, f = e & 63;
        float inv = exp2f(-(float)f * (13.287712379549449f / 64.0f));
        float fr = (float)s * inv;
        float sn, cs; sincosf(fr, &sn, &cs);
        rt[e] = make_float2(cs, sn);
    }
}

// ---------------- down GEMM (K-split): tpart[sp][m][r] = sum_{d in split} in[m][d] * At[r][d]
template<int IN_BF16, int WRITE_SS>
__global__ __launch_bounds__(256) void down_g(const void* __restrict__ inp,
                                              const unsigned short* __restrict__ At,
                                              float* __restrict__ tpart,
                                              float* __restrict__ sspart){
    __shared__ char xt[8192];
    __shared__ char at[8192];
    int tid = threadIdx.x;
    int m0 = blockIdx.x * 64, sp = blockIdx.y;
    int row = tid >> 2, q4 = tid & 3;
    int w = tid >> 6, lane = tid & 63, l4 = lane >> 4, lm = lane & 15;
    int swz = (row & 7) << 4;
    float ss = 0.f;
    f32x4 acc[4];
    #pragma unroll
    for (int nt = 0; nt < 4; ++nt) acc[nt] = (f32x4){0.f,0.f,0.f,0.f};

    float4 xr[4]; uint4 xrb[2]; uint4 ar[2];
    #define LOADC(c) { int k0 = sp * 256 + (c) * 64; \
        if (!IN_BF16){ const float4* s = (const float4*)((const float*)inp + (size_t)(m0+row)*1024 + k0 + q4*16); \
            xr[0]=s[0]; xr[1]=s[1]; xr[2]=s[2]; xr[3]=s[3]; } \
        else { const uint4* s = (const uint4*)((const unsigned short*)inp + (size_t)(m0+row)*1024 + k0 + q4*16); \
            xrb[0]=s[0]; xrb[1]=s[1]; } \
        const uint4* a = (const uint4*)(At + (size_t)row*1024 + k0 + q4*16); \
        ar[0]=a[0]; ar[1]=a[1]; }

    LOADC(0);
    for (int c = 0; c < 4; ++c){
        int b0 = row * 128 + ((q4 * 32) ^ swz);
        int b1 = row * 128 + ((q4 * 32 + 16) ^ swz);
        if (!IN_BF16){
            if (WRITE_SS){
                #pragma unroll
                for (int i = 0; i < 4; ++i)
                    ss += xr[i].x*xr[i].x + xr[i].y*xr[i].y + xr[i].z*xr[i].z + xr[i].w*xr[i].w;
            }
            uint4 p0 = {pk2(xr[0].x,xr[0].y), pk2(xr[0].z,xr[0].w), pk2(xr[1].x,xr[1].y), pk2(xr[1].z,xr[1].w)};
            uint4 p1 = {pk2(xr[2].x,xr[2].y), pk2(xr[2].z,xr[2].w), pk2(xr[3].x,xr[3].y), pk2(xr[3].z,xr[3].w)};
            *(uint4*)(xt + b0) = p0; *(uint4*)(xt + b1) = p1;
        } else {
            *(uint4*)(xt + b0) = xrb[0]; *(uint4*)(xt + b1) = xrb[1];
        }
        *(uint4*)(at + b0) = ar[0]; *(uint4*)(at + b1) = ar[1];
        __syncthreads();
        if (c < 3) LOADC(c + 1);
        #pragma unroll
        for (int ks = 0; ks < 2; ++ks){
            int arow = 16 * w + lm;
            bf16x8 af = *(const bf16x8*)(xt + arow * 128 + ((ks*64 + l4*16) ^ ((arow & 7) << 4)));
            #pragma unroll
            for (int nt = 0; nt < 4; ++nt){
                int brow = nt * 16 + lm;
                bf16x8 bf = *(const bf16x8*)(at + brow * 128 + ((ks*64 + l4*16) ^ ((brow & 7) << 4)));
                acc[nt] = __builtin_amdgcn_mfma_f32_16x16x32_bf16(af, bf, acc[nt], 0, 0, 0);
            }
        }
        __syncthreads();
    }
    #undef LOADC
    if (!IN_BF16 && WRITE_SS){
        ss += __shfl_xor(ss, 1); ss += __shfl_xor(ss, 2);
        if (q4 == 0) sspart[sp * Mn + m0 + row] = ss;
    }
    #pragma unroll
    for (int nt = 0; nt < 4; ++nt)
        #pragma unroll
        for (int r = 0; r < 4; ++r){
            int ml = 16 * w + 4 * l4 + r;
            tpart[(size_t)sp * TSTRIDE + (size_t)(m0 + ml) * 64 + nt * 16 + lm] = acc[nt][r];
        }
}

// ---------------- stage t tile (sum 4 K-split partials, optional rms scale) into swizzled LDS
template<int DORMS>
__device__ __forceinline__ void stage_t(char* tt, const float* __restrict__ tpart,
                                        const float* __restrict__ sspart, int m0, int tid){
    int row = tid >> 2, q4 = tid & 3;
    const float* bp = tpart + (size_t)(m0 + row) * 64 + q4 * 16;
    float4 s[4];
    #pragma unroll
    for (int i = 0; i < 4; ++i){
        float4 a = ((const float4*)(bp + 0 * TSTRIDE))[i];
        float4 b = ((const float4*)(bp + 1 * TSTRIDE))[i];
        float4 c = ((const float4*)(bp + 2 * TSTRIDE))[i];
        float4 d = ((const float4*)(bp + 3 * TSTRIDE))[i];
        s[i] = make_float4(a.x+b.x+c.x+d.x, a.y+b.y+c.y+d.y, a.z+b.z+c.z+d.z, a.w+b.w+c.w+d.w);
    }
    float rr = 1.f;
    if (DORMS){
        int m = m0 + row;
        float ssum = sspart[m] + sspart[Mn + m] + sspart[2*Mn + m] + sspart[3*Mn + m];
        rr = rsqrtf(ssum * (1.f / 1024.f) + 1.1920929e-07f);
    }
    #pragma unroll
    for (int i = 0; i < 4; ++i){ s[i].x*=rr; s[i].y*=rr; s[i].z*=rr; s[i].w*=rr; }
    int swz = (row & 7) << 4;
    uint4 p0 = {pk2(s[0].x,s[0].y), pk2(s[0].z,s[0].w), pk2(s[1].x,s[1].y), pk2(s[1].z,s[1].w)};
    uint4 p1 = {pk2(s[2].x,s[2].y), pk2(s[2].z,s[2].w), pk2(s[3].x,s[3].y), pk2(s[3].z,s[3].w)};
    *(uint4*)(tt + row * 128 + ((q4 * 32) ^ swz)) = p0;
    *(uint4*)(tt + row * 128 + ((q4 * 32 + 16) ^ swz)) = p1;
}

// ---------------- up GEMM: M-tile 32 x N-chunk 256, K=64
template<int SILU, int HASBASE, int OUT_BF16, int DORMS>
__global__ __launch_bounds__(256) void up_g(const float* __restrict__ tpart,
                                            const float* __restrict__ sspart,
                                            const unsigned short* __restrict__ Bt,
                                            const float* base,
                                            void* __restrict__ outp){
    __shared__ char tt[4096];
    __shared__ char bb[32768];
    int tid = threadIdx.x;
    int m0 = blockIdx.x * 32, n0 = blockIdx.y * 256;
    int w = tid >> 6, lane = tid & 63, l4 = lane >> 4, lm = lane & 15;
    int wm = w & 1, wn = w >> 1;
    if (tid < 128) stage_t<DORMS>(tt, tpart, sspart, m0, tid);
    {
        const uint4* s = (const uint4*)(Bt + (size_t)(n0 + tid) * 64);
        #pragma unroll
        for (int j = 0; j < 8; ++j){
            uint4 v = s[j];
            *(uint4*)(bb + tid * 128 + ((j * 16) ^ ((tid & 7) << 4))) = v;
        }
    }
    __syncthreads();
    bf16x8 af[2];
    #pragma unroll
    for (int ks = 0; ks < 2; ++ks){
        int arow = 16 * wm + lm;
        af[ks] = *(const bf16x8*)(tt + arow * 128 + ((ks*64 + l4*16) ^ ((arow & 7) << 4)));
    }
    f32x4 acc[8];
    #pragma unroll
    for (int nt = 0; nt < 8; ++nt) acc[nt] = (f32x4){0.f,0.f,0.f,0.f};
    #pragma unroll
    for (int nt = 0; nt < 8; ++nt){
        int brow = wn * 128 + nt * 16 + lm;
        #pragma unroll
        for (int ks = 0; ks < 2; ++ks){
            bf16x8 bf = *(const bf16x8*)(bb + brow * 128 + ((ks*64 + l4*16) ^ ((brow & 7) << 4)));
            acc[nt] = __builtin_amdgcn_mfma_f32_16x16x32_bf16(af[ks], bf, acc[nt], 0, 0, 0);
        }
    }
    #pragma unroll
    for (int nt = 0; nt < 8; ++nt)
        #pragma unroll
        for (int r = 0; r < 4; ++r){
            int m = m0 + 16 * wm + 4 * l4 + r;
            int n = n0 + wn * 128 + nt * 16 + lm;
            float v = acc[nt][r];
            if (SILU) v = v / (1.f + __expf(-v));
            if (HASBASE) v += base[(size_t)m * 1024 + n];
            if (OUT_BF16) ((unsigned short*)outp)[(size_t)m * 1024 + n] = f2bf(v);
            else          ((float*)outp)[(size_t)m * 1024 + n] = v;
        }
}

// ---------------- fused QKV up-proj + RoPE; K,V written as pre-swizzled tile images
// Kimg: [bh][tile32][imgrow64][256B swz], imgrow rho(t)=16*(t&3)+(t>>2) holds key t;
// Vimg: [bh][tile32][d128][128B swz] (natural key order in columns)
__global__ __launch_bounds__(256) void qkv_g(const float* __restrict__ tpart,
                                             const float* __restrict__ sspart,
                                             const unsigned short* __restrict__ Btq,
                                             const unsigned short* __restrict__ Btk,
                                             const unsigned short* __restrict__ Btv,
                                             const float2* __restrict__ rt,
                                             unsigned short* __restrict__ qout,
                                             char* __restrict__ Kimg,
                                             char* __restrict__ Vimg){
    __shared__ char tt[8192];
    __shared__ char bb[32768];
    int tid = threadIdx.x;
    int m0 = blockIdx.x * 64, n0 = blockIdx.y * 256;
    int b = m0 >> 11, s0 = m0 & (Sn - 1);
    int h0 = n0 >> 7;
    int w = tid >> 6, lane = tid & 63, l4 = lane >> 4, lm = lane & 15;
    stage_t<1>(tt, tpart, sspart, m0, tid);
    #define STAGE_B(SRC) { const uint4* s = (const uint4*)((SRC) + (size_t)(n0 + tid) * 64); \
        _Pragma("unroll") for (int j = 0; j < 8; ++j){ uint4 v = s[j]; \
            *(uint4*)(bb + tid * 128 + ((j * 16) ^ ((tid & 7) << 4))) = v; } }
    STAGE_B(Btq);
    __syncthreads();
    bf16x8 af[2];
    #pragma unroll
    for (int ks = 0; ks < 2; ++ks){
        int arow = 16 * w + lm;
        af[ks] = *(const bf16x8*)(tt + arow * 128 + ((ks*64 + l4*16) ^ ((arow & 7) << 4)));
    }
    f32x4 acc[16];
    float2 cs[4][4];
    #pragma unroll
    for (int ntb = 0; ntb < 4; ++ntb)
        #pragma unroll
        for (int r = 0; r < 4; ++r)
            cs[ntb][r] = rt[(size_t)(s0 + 16*w + 4*l4 + r) * 64 + ntb * 16 + lm];

    #define MMUL() { _Pragma("unroll") for (int nt = 0; nt < 16; ++nt) acc[nt] = (f32x4){0.f,0.f,0.f,0.f}; \
        _Pragma("unroll") for (int nt = 0; nt < 16; ++nt){ int brow = nt * 16 + lm; \
            _Pragma("unroll") for (int ks = 0; ks < 2; ++ks){ \
                bf16x8 bf = *(const bf16x8*)(bb + brow * 128 + ((ks*64 + l4*16) ^ ((brow & 7) << 4))); \
                acc[nt] = __builtin_amdgcn_mfma_f32_16x16x32_bf16(af[ks], bf, acc[nt], 0, 0, 0); } } }

    #define ROPE() { _Pragma("unroll") for (int g = 0; g < 2; ++g) \
        _Pragma("unroll") for (int ntb = 0; ntb < 4; ++ntb){ int lo = g*8 + ntb, hi = lo + 4; \
            _Pragma("unroll") for (int r = 0; r < 4; ++r){ float2 c = cs[ntb][r]; \
                float a = acc[lo][r], bq = acc[hi][r]; \
                acc[lo][r] = a * c.x + bq * c.y; acc[hi][r] = -a * c.y + bq * c.x; } } }

    #define BOUNCE() { \
        _Pragma("unroll") for (int nt = 0; nt < 16; ++nt) \
            _Pragma("unroll") for (int r = 0; r < 4; ++r){ \
                int nl = nt * 16 + lm, ml2 = 16 * w + 4 * l4 + r; \
                *(unsigned short*)(bb + ml2 * 512 + ((nl * 2) ^ ((ml2 & 7) << 4))) = f2bf(acc[nt][r]); } \
        __syncthreads(); }

    // ---- Q -> [bh,s,hd]  (pre-scaled by 1/sqrt(128)*log2e via Btq)
    MMUL(); ROPE();
    __syncthreads();
    BOUNCE();
    {
        int ml = tid >> 2, seg = tid & 3;
        int head = h0 + (seg >> 1), hd0q = (seg & 1) * 64;
        size_t dstbase = (((size_t)(b * 8 + head) * Sn + (s0 + ml)) * 128 + hd0q);
        #pragma unroll
        for (int j = 0; j < 8; ++j){
            uint4 v = *(const uint4*)(bb + ml * 512 + ((seg * 128 + j * 16) ^ ((ml & 7) << 4)));
            *(uint4*)(qout + dstbase + j * 8) = v;
        }
    }
    __syncthreads();
    // ---- K -> swizzled tile image, permuted rows (image row rho(ml) holds key s0+ml)
    STAGE_B(Btk);
    __syncthreads();
    MMUL(); ROPE();
    __syncthreads();
    BOUNCE();
    {
        int ml = tid >> 2, seg = tid & 3;
        int hd0q = (seg & 1) * 64;
        int head = h0 + (seg >> 1);
        int pr = 16 * (ml & 3) + (ml >> 2);   // permuted image row
        size_t rowb = (((size_t)(b * 8 + head) * 32 + (s0 >> 6)) * 64 + pr) * 256;
        #pragma unroll
        for (int j = 0; j < 8; ++j){
            uint4 v = *(const uint4*)(bb + ml * 512 + ((seg * 128 + j * 16) ^ ((ml & 7) << 4)));
            int cb = hd0q * 2 + j * 16;
            *(uint4*)(Kimg + rowb + (cb ^ ((pr & 7) << 4))) = v;
        }
    }
    __syncthreads();
    // ---- V -> transposed swizzled tile image (natural key order)
    STAGE_B(Btv);
    __syncthreads();
    MMUL();
    __syncthreads();
    #pragma unroll
    for (int nt = 0; nt < 16; ++nt)
        #pragma unroll
        for (int r = 0; r < 4; ++r){
            int nl = nt * 16 + lm, ml2 = 16 * w + 4 * l4 + r;
            *(unsigned short*)(bb + nl * 128 + ((ml2 * 2) ^ ((nl & 7) << 4))) = f2bf(acc[nt][r]);
        }
    __syncthreads();
    {
        int head = h0 + (tid >> 7), d = tid & 127;
        size_t rowb = (((size_t)(b * 8 + head) * 32 + (s0 >> 6)) * 128 + d) * 128;
        #pragma unroll
        for (int j = 0; j < 8; ++j){
            uint4 v = *(const uint4*)(bb + tid * 128 + ((j * 16) ^ ((tid & 7) << 4)));
            *(uint4*)(Vimg + rowb + ((j * 16) ^ ((d & 7) << 4))) = v;
        }
    }
    #undef STAGE_B
    #undef MMUL
    #undef ROPE
    #undef BOUNCE
}

// ---------------- K-split flash attention: static-offset softmax p=2^(s-OFF)
// 384 blocks, XCD-remapped so each bh pair stays on one XCD (K/V L2-resident).
// grp0: (J=8+g, slice0, 16 tiles); grp1: (J=15-g, slice1, 2J-14 tiles);
// grp2: (J=7-g, direct, 2J+2 tiles). 4 waves, 32 q-rows/wave. dbuf 80KB LDS.
__global__ __launch_bounds__(256, 2) void attn2_kernel(const unsigned short* __restrict__ qb,
                                                       const char* __restrict__ Kimg,
                                                       const char* __restrict__ Vimg,
                                                       unsigned short* __restrict__ ybf,
                                                       float* __restrict__ pacc,
                                                       float* __restrict__ pl){
    __shared__ uint4 smem4[81920 / 16];
    char* smem = (char*)smem4;
    int tid = threadIdx.x;
    int w = tid >> 6, lane = tid & 63, l4 = lane >> 4, lm = lane & 15;
    // XCD-aware remap: blockIdx i -> XCD x = i&7 handles bh {2x, 2x+1}
    int i = blockIdx.x;
    int xg = i & 7, j5 = i >> 3;          // j5 in [0,48)
    int bh = 2 * xg + (j5 & 1);
    int slot = j5 >> 1;                   // 0..23
    int grp = slot >> 3, g = slot & 7;
    int J, t0, niters, direct, slice;
    if (grp == 0){ J = 8 + g;  t0 = 0;  niters = 16;         direct = 0; slice = (bh * 8 + g) * 2; }
    else if (grp == 1){ J = 15 - g; t0 = 16; niters = 2 * J - 14; direct = 0; slice = (bh * 8 + (J - 8)) * 2 + 1; }
    else { J = 7 - g;  t0 = 0;  niters = 2 * J + 2;  direct = 1; slice = 0; }
    int b = bh >> 3, h = bh & 7;
    int qrow0w = 128 * J + 32 * w;
    int wqmax = qrow0w + 31;

    bf16x8 qf[2][4];
    #pragma unroll
    for (int f = 0; f < 2; ++f){
        const unsigned short* qg = qb + ((size_t)bh * Sn + qrow0w + 16 * f + lm) * HDn;
        #pragma unroll
        for (int df = 0; df < 4; ++df)
            qf[f][df] = *(const bf16x8*)(qg + df * 32 + l4 * 8);
    }
    f32x4 acc[2][8];
    #pragma unroll
    for (int f = 0; f < 2; ++f)
        #pragma unroll
        for (int dg = 0; dg < 8; ++dg) acc[f][dg] = (f32x4){0.f,0.f,0.f,0.f};
    float lp[2][4];
    #pragma unroll
    for (int f = 0; f < 2; ++f)
        #pragma unroll
        for (int r = 0; r < 4; ++r) lp[f][r] = 0.f;

    const float OFF = 11.541560327111708f;   // 8 * log2(e)
    size_t imgbase = (size_t)bh * 32 * 16384;

    uint4 sk[4], sv4[4];
    {   // prologue: stage t0 -> buf0
        size_t tb = imgbase + (size_t)t0 * 16384;
        #pragma unroll
        for (int i2 = 0; i2 < 4; ++i2){
            sk[i2]  = *(const uint4*)(Kimg + tb + i2 * 4096 + tid * 16);
            sv4[i2] = *(const uint4*)(Vimg + tb + i2 * 4096 + tid * 16);
        }
        #pragma unroll
        for (int i2 = 0; i2 < 4; ++i2){
            *(uint4*)(smem + i2 * 4096 + tid * 16) = sk[i2];
            *(uint4*)(smem + 16384 + i2 * 4096 + tid * 16) = sv4[i2];
        }
    }
    __syncthreads();

    for (int it = 0; it < niters; ++it){
        int t = t0 + it;
        int bsel = (it & 1) << 15;
        if (it + 1 < niters){
            size_t tb = imgbase + (size_t)(t + 1) * 16384;
            #pragma unroll
            for (int i2 = 0; i2 < 4; ++i2){
                sk[i2]  = *(const uint4*)(Kimg + tb + i2 * 4096 + tid * 16);
                sv4[i2] = *(const uint4*)(Vimg + tb + i2 * 4096 + tid * 16);
            }
        }
        if (64 * t <= wqmax){
            char* KL = smem + bsel;
            char* VL = smem + bsel + 16384;
            char* pb = smem + 65536 + (w << 12);
            f32x4 sf[2][4];
            #pragma unroll
            for (int kc = 0; kc < 4; ++kc){ sf[0][kc] = (f32x4){0.f,0.f,0.f,0.f}; sf[1][kc] = (f32x4){0.f,0.f,0.f,0.f}; }
            #pragma unroll
            for (int kc = 0; kc < 4; ++kc){
                int krow = 16 * kc + lm;
                int ksw = (krow & 7) << 4;
                #pragma unroll
                for (int df = 0; df < 4; ++df){
                    bf16x8 kf = *(const bf16x8*)(KL + krow * 256 + ((df * 64 + l4 * 16) ^ ksw));
                    sf[0][kc] = __builtin_amdgcn_mfma_f32_16x16x32_bf16(qf[0][df], kf, sf[0][kc], 0, 0, 0);
                    sf[1][kc] = __builtin_amdgcn_mfma_f32_16x16x32_bf16(qf[1][df], kf, sf[1][kc], 0, 0, 0);
                }
            }
            // lane's score sf[kc][r] is for TRUE key 64t + 4*lm + kc (permuted image)
            bool needmask = (64 * t + 63 > qrow0w);
            #pragma unroll
            for (int f = 0; f < 2; ++f){
                #pragma unroll
                for (int r = 0; r < 4; ++r){
                    float s0v = sf[f][0][r], s1v = sf[f][1][r],
                          s2v = sf[f][2][r], s3v = sf[f][3][r];
                    if (needmask){
                        int qr = qrow0w + 16 * f + 4 * l4 + r;
                        int j0k = 64 * t + 4 * lm;
                        s0v = (j0k     > qr) ? -1e30f : s0v;
                        s1v = (j0k + 1 > qr) ? -1e30f : s1v;
                        s2v = (j0k + 2 > qr) ? -1e30f : s2v;
                        s3v = (j0k + 3 > qr) ? -1e30f : s3v;
                    }
                    // static-offset softmax in exp2 domain (scale folded into Q)
                    float p0 = vexp2(s0v - OFF), p1 = vexp2(s1v - OFF),
                          p2 = vexp2(s2v - OFF), p3 = vexp2(s3v - OFF);
                    lp[f][r] += p0 + p1 + p2 + p3;
                    int prow = 16 * f + 4 * l4 + r;
                    uint2 pkd = {pk2(p0, p1), pk2(p2, p3)};
                    *(uint2*)(pb + prow * 128 + ((lm * 8) ^ ((prow & 7) << 4))) = pkd;
                }
            }
            #pragma unroll
            for (int ks = 0; ks < 2; ++ks){
                int pcol = (ks * 64 + l4 * 16) ^ ((lm & 7) << 4);
                bf16x8 pa0 = *(const bf16x8*)(pb + lm * 128 + pcol);
                bf16x8 pa1 = *(const bf16x8*)(pb + (16 + lm) * 128 + pcol);
                #pragma unroll
                for (int dg = 0; dg < 8; ++dg){
                    int vrow = 16 * dg + lm;
                    bf16x8 vf = *(const bf16x8*)(VL + vrow * 128 + ((ks * 64 + l4 * 16) ^ ((vrow & 7) << 4)));
                    acc[0][dg] = __builtin_amdgcn_mfma_f32_16x16x32_bf16(pa0, vf, acc[0][dg], 0, 0, 0);
                    acc[1][dg] = __builtin_amdgcn_mfma_f32_16x16x32_bf16(pa1, vf, acc[1][dg], 0, 0, 0);
                }
            }
        }
        if (it + 1 < niters){
            int ob = bsel ^ 32768;
            #pragma unroll
            for (int i2 = 0; i2 < 4; ++i2){
                *(uint4*)(smem + ob + i2 * 4096 + tid * 16) = sk[i2];
                *(uint4*)(smem + ob + 16384 + i2 * 4096 + tid * 16) = sv4[i2];
            }
        }
        __syncthreads();
    }
    // epilogue: one cross-lane reduce of l per row (deferred from the loop)
    float lsum[2][4];
    #pragma unroll
    for (int f = 0; f < 2; ++f)
        #pragma unroll
        for (int r = 0; r < 4; ++r){
            float l_ = lp[f][r];
            l_ += __shfl_xor(l_, 1);
            l_ += __shfl_xor(l_, 2);
            l_ += __shfl_xor(l_, 4);
            l_ += __shfl_xor(l_, 8);
            lsum[f][r] = l_;
        }
    if (direct){
        #pragma unroll
        for (int f = 0; f < 2; ++f)
            #pragma unroll
            for (int r = 0; r < 4; ++r){
                float inv = 1.f / lsum[f][r];
                int row = qrow0w + 16 * f + 4 * l4 + r;
                unsigned short* yr = ybf + ((size_t)b * Sn + row) * Dn + h * HDn;
                #pragma unroll
                for (int dg = 0; dg < 8; ++dg)
                    yr[16 * dg + lm] = f2bf(acc[f][dg][r] * inv);
            }
    } else {
        float* pa_ = pacc + (size_t)slice * 16384;
        #pragma unroll
        for (int f = 0; f < 2; ++f)
            #pragma unroll
            for (int r = 0; r < 4; ++r){
                int row = 32 * w + 16 * f + 4 * l4 + r;
                #pragma unroll
                for (int dg = 0; dg < 8; ++dg)
                    pa_[row * 128 + 16 * dg + lm] = acc[f][dg][r];
                if (lm == 0)
                    pl[slice * 128 + row] = lsum[f][r];
            }
    }
}

// ---------------- combine two K-slices -> y (bf16): O = (A0+A1)/(l0+l1)
__global__ __launch_bounds__(256) void comb_g(const float* __restrict__ pacc,
                                              const float* __restrict__ pl,
                                              unsigned short* __restrict__ ybf){
    int bh = blockIdx.x >> 3, g = blockIdx.x & 7, J = 8 + g;
    int s0 = (bh * 8 + g) * 2, s1 = s0 + 1;
    int tid = threadIdx.x;
    __shared__ float wsum[128];
    if (tid < 128)
        wsum[tid] = 1.f / (pl[s0 * 128 + tid] + pl[s1 * 128 + tid]);
    __syncthreads();
    int b = bh >> 3, h = bh & 7;
    const float4* p0 = (const float4*)(pacc + (size_t)s0 * 16384);
    const float4* p1 = (const float4*)(pacc + (size_t)s1 * 16384);
    #pragma unroll
    for (int i = 0; i < 16; ++i){
        int idx = i * 256 + tid;
        int row = idx >> 5, c4 = idx & 31;
        float4 a0 = p0[idx], a1 = p1[idx];
        float W = wsum[row];
        ushort4 o;
        o.x = f2bf((a0.x + a1.x) * W);
        o.y = f2bf((a0.y + a1.y) * W);
        o.z = f2bf((a0.z + a1.z) * W);
        o.w = f2bf((a0.w + a1.w) * W);
        int srow = 128 * J + row;
        *(ushort4*)(ybf + ((size_t)b * Sn + srow) * Dn + h * HDn + c4 * 4) = o;
    }
}

extern "C" void kernel_launch(void* const* d_in, const int* in_sizes, int n_in,
                              void* d_out, int out_size, void* d_ws, size_t ws_size,
                              hipStream_t stream){
    const float* x      = (const float*)d_in[0];
    const float* A      = (const float*)d_in[1];
    const float* Bm     = (const float*)d_in[2];
    const float* C_q    = (const float*)d_in[3];
    const float* C_k    = (const float*)d_in[4];
    const float* C_v    = (const float*)d_in[5];
    const float* C_o    = (const float*)d_in[6];
    const float* C_fc   = (const float*)d_in[7];
    const float* C_proj = (const float*)d_in[8];
    const float* scale1 = (const float*)d_in[9];
    const float* scale2 = (const float*)d_in[10];
    float* out = (float*)d_out;

    char* ws = (char*)d_ws;
    size_t off = 0;
    auto alloc = [&](size_t bytes)->char*{ char* p = ws + off; off += (bytes + 255) & ~(size_t)255; return p; };
    unsigned short* qb   = (unsigned short*)alloc((size_t)Mn * Dn * 2);   // 8MB
    char*           Kimg = alloc((size_t)16 * 32 * 16384);                // 8MB
    char*           Vimg = alloc((size_t)16 * 32 * 16384);                // 8MB
    unsigned short* ybf  = (unsigned short*)alloc((size_t)Mn * Dn * 2);   // 8MB
    float*          pacc = (float*)alloc((size_t)256 * 16384 * 4);        // 16MB
    float*          pl   = (float*)alloc((size_t)256 * 128 * 4);          // 128KB
    float*          tp   = (float*)alloc(4 * TSTRIDE * 4);                // 4MB
    float*          ssp  = (float*)alloc(4 * (size_t)Mn * 4);             // 64KB
    unsigned short* At0  = (unsigned short*)alloc(65536 * 2);
    unsigned short* At1  = (unsigned short*)alloc(65536 * 2);
    unsigned short* At2  = (unsigned short*)alloc(65536 * 2);
    unsigned short* Btq  = (unsigned short*)alloc(65536 * 2);
    unsigned short* Btk  = (unsigned short*)alloc(65536 * 2);
    unsigned short* Btv  = (unsigned short*)alloc(65536 * 2);
    unsigned short* Bto  = (unsigned short*)alloc(65536 * 2);
    unsigned short* Btfc = (unsigned short*)alloc(65536 * 2);
    unsigned short* Btpr = (unsigned short*)alloc(65536 * 2);
    float2*         rt   = (float2*)alloc((size_t)Sn * 64 * 8);           // 1MB
    unsigned short* mb   = (unsigned short*)Kimg;  // overlay: Kimg dead after attention

    prep_g<<<2816, 256, 0, stream>>>(A, Bm, C_q, C_k, C_v, C_o, C_fc, C_proj,
                                     scale1, scale2, At0, At1, At2,
                                     Btq, Btk, Btv, Bto, Btfc, Btpr, rt);
    down_g<0, 1><<<dim3(Mn / 64, 4), 256, 0, stream>>>(x, At1, tp, ssp);
    qkv_g<<<dim3(Mn / 64, 4), 256, 0, stream>>>(tp, ssp, Btq, Btk, Btv, rt, qb, Kimg, Vimg);
    attn2_kernel<<<384, 256, 0, stream>>>(qb, Kimg, Vimg, ybf, pacc, pl);
    comb_g<<<128, 256, 0, stream>>>(pacc, pl, ybf);
    down_g<1, 0><<<dim3(Mn / 64, 4), 256, 0, stream>>>(ybf, At0, tp, nullptr);
    up_g<0, 1, 0, 0><<<dim3(Mn / 32, 4), 256, 0, stream>>>(tp, nullptr, Bto, x, out);
    down_g<0, 1><<<dim3(Mn / 64, 4), 256, 0, stream>>>(out, At2, tp, ssp);
    up_g<1, 0, 1, 1><<<dim3(Mn / 32, 4), 256, 0, stream>>>(tp, ssp, Btfc, nullptr, mb);
    down_g<1, 0><<<dim3(Mn / 64, 4), 256, 0, stream>>>(mb, At0, tp, nullptr);
    up_g<0, 1, 0, 0><<<dim3(Mn / 32, 4), 256, 0, stream>>>(tp, nullptr, Btpr, out, out);
}

// Round 11
// 148.418 us; speedup vs baseline: 1.9911x; 1.0912x over previous
//
#include <hip/hip_runtime.h>

// HolographicBlock: B=2, S=2048, D=1024, R=64, H=8, HD=128
// Projections = bf16 MFMA GEMMs; fused up->down kernels (updown_g) eliminate
// the out re-read and the mb intermediate entirely.
// Attention = R10 structure + s_setprio around compute.

#define Bn 2
#define Sn 2048
#define Dn 1024
#define Rn 64
#define Hn 8
#define HDn 128
#define Mn (Bn*Sn)   // 4096 rows
#define TSTRIDE ((size_t)Mn * Rn)

typedef __bf16 bf16x8 __attribute__((ext_vector_type(8)));
typedef float f32x4 __attribute__((ext_vector_type(4)));

__device__ __forceinline__ float bf2f(unsigned short u){
    union { unsigned int i; float f; } x; x.i = ((unsigned int)u) << 16; return x.f;
}
__device__ __forceinline__ unsigned short f2bf(float f){
    union { float f; unsigned int i; } x; x.f = f;
    unsigned int r = x.i + 0x7fffu + ((x.i >> 16) & 1u);
    return (unsigned short)(r >> 16);
}
__device__ __forceinline__ unsigned int pk2(float a, float b){
    unsigned int r;
    asm("v_cvt_pk_bf16_f32 %0, %1, %2" : "=v"(r) : "v"(a), "v"(b));
    return r;
}
__device__ __forceinline__ float vexp2(float x){
    float r;
    asm("v_exp_f32 %0, %1" : "=v"(r) : "v"(x));
    return r;
}

// ---------------- prep: bf16 transposed weights + rope table
__global__ __launch_bounds__(256) void prep_g(const float* __restrict__ A,
                                              const float* __restrict__ Bsrc,
                                              const float* __restrict__ Cq, const float* __restrict__ Ck,
                                              const float* __restrict__ Cv, const float* __restrict__ Co,
                                              const float* __restrict__ Cfc, const float* __restrict__ Cpr,
                                              const float* __restrict__ s1, const float* __restrict__ s2,
                                              unsigned short* __restrict__ At0, unsigned short* __restrict__ At1,
                                              unsigned short* __restrict__ At2,
                                              unsigned short* __restrict__ Btq, unsigned short* __restrict__ Btk,
                                              unsigned short* __restrict__ Btv, unsigned short* __restrict__ Bto,
                                              unsigned short* __restrict__ Btfc, unsigned short* __restrict__ Btpr,
                                              float2* __restrict__ rt){
    int idx = blockIdx.x * 256 + threadIdx.x;
    if (idx < 3 * 65536){
        int v = idx >> 16, e = idx & 65535;
        int r = e >> 10, d = e & 1023;
        float sc = (v == 0) ? 1.f : (v == 1 ? s1[d] : s2[d]);
        unsigned short val = f2bf(A[d * 64 + r] * sc);
        (v == 0 ? At0 : v == 1 ? At1 : At2)[e] = val;
    } else if (idx < 9 * 65536){
        int v = (idx - 3 * 65536) >> 16, e = idx & 65535;
        int d = e >> 6, r = e & 63;
        const float* C = v==0?Cq : v==1?Ck : v==2?Cv : v==3?Co : v==4?Cfc : Cpr;
        float extra = (v == 0) ? (0.08838834764831845f * 1.4426950408889634f) : 1.f;
        unsigned short val = f2bf(Bsrc[r * 1024 + d] * C[r] * extra);
        (v==0?Btq : v==1?Btk : v==2?Btv : v==3?Bto : v==4?Btfc : Btpr)[e] = val;
    } else if (idx < 9 * 65536 + Sn * 64){
        int e = idx - 9 * 65536;
        int s = e >> 6, f = e & 63;
        float inv = exp2f(-(float)f * (13.287712379549449f / 64.0f));
        float fr = (float)s * inv;
        float sn, cs; sincosf(fr, &sn, &cs);
        rt[e] = make_float2(cs, sn);
    }
}

// ---------------- down GEMM (K-split): tpart[sp][m][r] = sum_{d in split} in[m][d] * At[r][d]
template<int IN_BF16, int WRITE_SS>
__global__ __launch_bounds__(256) void down_g(const void* __restrict__ inp,
                                              const unsigned short* __restrict__ At,
                                              float* __restrict__ tpart,
                                              float* __restrict__ sspart){
    __shared__ char xt[8192];
    __shared__ char at[8192];
    int tid = threadIdx.x;
    int m0 = blockIdx.x * 64, sp = blockIdx.y;
    int row = tid >> 2, q4 = tid & 3;
    int w = tid >> 6, lane = tid & 63, l4 = lane >> 4, lm = lane & 15;
    int swz = (row & 7) << 4;
    float ss = 0.f;
    f32x4 acc[4];
    #pragma unroll
    for (int nt = 0; nt < 4; ++nt) acc[nt] = (f32x4){0.f,0.f,0.f,0.f};

    float4 xr[4]; uint4 xrb[2]; uint4 ar[2];
    #define LOADC(c) { int k0 = sp * 256 + (c) * 64; \
        if (!IN_BF16){ const float4* s = (const float4*)((const float*)inp + (size_t)(m0+row)*1024 + k0 + q4*16); \
            xr[0]=s[0]; xr[1]=s[1]; xr[2]=s[2]; xr[3]=s[3]; } \
        else { const uint4* s = (const uint4*)((const unsigned short*)inp + (size_t)(m0+row)*1024 + k0 + q4*16); \
            xrb[0]=s[0]; xrb[1]=s[1]; } \
        const uint4* a = (const uint4*)(At + (size_t)row*1024 + k0 + q4*16); \
        ar[0]=a[0]; ar[1]=a[1]; }

    LOADC(0);
    for (int c = 0; c < 4; ++c){
        int b0 = row * 128 + ((q4 * 32) ^ swz);
        int b1 = row * 128 + ((q4 * 32 + 16) ^ swz);
        if (!IN_BF16){
            if (WRITE_SS){
                #pragma unroll
                for (int i = 0; i < 4; ++i)
                    ss += xr[i].x*xr[i].x + xr[i].y*xr[i].y + xr[i].z*xr[i].z + xr[i].w*xr[i].w;
            }
            uint4 p0 = {pk2(xr[0].x,xr[0].y), pk2(xr[0].z,xr[0].w), pk2(xr[1].x,xr[1].y), pk2(xr[1].z,xr[1].w)};
            uint4 p1 = {pk2(xr[2].x,xr[2].y), pk2(xr[2].z,xr[2].w), pk2(xr[3].x,xr[3].y), pk2(xr[3].z,xr[3].w)};
            *(uint4*)(xt + b0) = p0; *(uint4*)(xt + b1) = p1;
        } else {
            *(uint4*)(xt + b0) = xrb[0]; *(uint4*)(xt + b1) = xrb[1];
        }
        *(uint4*)(at + b0) = ar[0]; *(uint4*)(at + b1) = ar[1];
        __syncthreads();
        if (c < 3) LOADC(c + 1);
        #pragma unroll
        for (int ks = 0; ks < 2; ++ks){
            int arow = 16 * w + lm;
            bf16x8 af = *(const bf16x8*)(xt + arow * 128 + ((ks*64 + l4*16) ^ ((arow & 7) << 4)));
            #pragma unroll
            for (int nt = 0; nt < 4; ++nt){
                int brow = nt * 16 + lm;
                bf16x8 bf = *(const bf16x8*)(at + brow * 128 + ((ks*64 + l4*16) ^ ((brow & 7) << 4)));
                acc[nt] = __builtin_amdgcn_mfma_f32_16x16x32_bf16(af, bf, acc[nt], 0, 0, 0);
            }
        }
        __syncthreads();
    }
    #undef LOADC
    if (!IN_BF16 && WRITE_SS){
        ss += __shfl_xor(ss, 1); ss += __shfl_xor(ss, 2);
        if (q4 == 0) sspart[sp * Mn + m0 + row] = ss;
    }
    #pragma unroll
    for (int nt = 0; nt < 4; ++nt)
        #pragma unroll
        for (int r = 0; r < 4; ++r){
            int ml = 16 * w + 4 * l4 + r;
            tpart[(size_t)sp * TSTRIDE + (size_t)(m0 + ml) * 64 + nt * 16 + lm] = acc[nt][r];
        }
}

// ---------------- stage t tile (sum 4 K-split partials, optional rms scale) into swizzled LDS
template<int DORMS>
__device__ __forceinline__ void stage_t(char* tt, const float* __restrict__ tpart,
                                        const float* __restrict__ sspart, int m0, int tid){
    int row = tid >> 2, q4 = tid & 3;
    const float* bp = tpart + (size_t)(m0 + row) * 64 + q4 * 16;
    float4 s[4];
    #pragma unroll
    for (int i = 0; i < 4; ++i){
        float4 a = ((const float4*)(bp + 0 * TSTRIDE))[i];
        float4 b = ((const float4*)(bp + 1 * TSTRIDE))[i];
        float4 c = ((const float4*)(bp + 2 * TSTRIDE))[i];
        float4 d = ((const float4*)(bp + 3 * TSTRIDE))[i];
        s[i] = make_float4(a.x+b.x+c.x+d.x, a.y+b.y+c.y+d.y, a.z+b.z+c.z+d.z, a.w+b.w+c.w+d.w);
    }
    float rr = 1.f;
    if (DORMS){
        int m = m0 + row;
        float ssum = sspart[m] + sspart[Mn + m] + sspart[2*Mn + m] + sspart[3*Mn + m];
        rr = rsqrtf(ssum * (1.f / 1024.f) + 1.1920929e-07f);
    }
    #pragma unroll
    for (int i = 0; i < 4; ++i){ s[i].x*=rr; s[i].y*=rr; s[i].z*=rr; s[i].w*=rr; }
    int swz = (row & 7) << 4;
    uint4 p0 = {pk2(s[0].x,s[0].y), pk2(s[0].z,s[0].w), pk2(s[1].x,s[1].y), pk2(s[1].z,s[1].w)};
    uint4 p1 = {pk2(s[2].x,s[2].y), pk2(s[2].z,s[2].w), pk2(s[3].x,s[3].y), pk2(s[3].z,s[3].w)};
    *(uint4*)(tt + row * 128 + ((q4 * 32) ^ swz)) = p0;
    *(uint4*)(tt + row * 128 + ((q4 * 32 + 16) ^ swz)) = p1;
}

// ---------------- up GEMM (final projection only): M-tile 32 x N-chunk 256
template<int SILU, int HASBASE, int OUT_BF16, int DORMS>
__global__ __launch_bounds__(256) void up_g(const float* __restrict__ tpart,
                                            const float* __restrict__ sspart,
                                            const unsigned short* __restrict__ Bt,
                                            const float* base,
                                            void* __restrict__ outp){
    __shared__ char tt[4096];
    __shared__ char bb[32768];
    int tid = threadIdx.x;
    int m0 = blockIdx.x * 32, n0 = blockIdx.y * 256;
    int w = tid >> 6, lane = tid & 63, l4 = lane >> 4, lm = lane & 15;
    int wm = w & 1, wn = w >> 1;
    if (tid < 128) stage_t<DORMS>(tt, tpart, sspart, m0, tid);
    {
        const uint4* s = (const uint4*)(Bt + (size_t)(n0 + tid) * 64);
        #pragma unroll
        for (int j = 0; j < 8; ++j){
            uint4 v = s[j];
            *(uint4*)(bb + tid * 128 + ((j * 16) ^ ((tid & 7) << 4))) = v;
        }
    }
    __syncthreads();
    bf16x8 af[2];
    #pragma unroll
    for (int ks = 0; ks < 2; ++ks){
        int arow = 16 * wm + lm;
        af[ks] = *(const bf16x8*)(tt + arow * 128 + ((ks*64 + l4*16) ^ ((arow & 7) << 4)));
    }
    f32x4 acc[8];
    #pragma unroll
    for (int nt = 0; nt < 8; ++nt) acc[nt] = (f32x4){0.f,0.f,0.f,0.f};
    #pragma unroll
    for (int nt = 0; nt < 8; ++nt){
        int brow = wn * 128 + nt * 16 + lm;
        #pragma unroll
        for (int ks = 0; ks < 2; ++ks){
            bf16x8 bf = *(const bf16x8*)(bb + brow * 128 + ((ks*64 + l4*16) ^ ((brow & 7) << 4)));
            acc[nt] = __builtin_amdgcn_mfma_f32_16x16x32_bf16(af[ks], bf, acc[nt], 0, 0, 0);
        }
    }
    #pragma unroll
    for (int nt = 0; nt < 8; ++nt)
        #pragma unroll
        for (int r = 0; r < 4; ++r){
            int m = m0 + 16 * wm + 4 * l4 + r;
            int n = n0 + wn * 128 + nt * 16 + lm;
            float v = acc[nt][r];
            if (SILU) v = v / (1.f + __expf(-v));
            if (HASBASE) v += base[(size_t)m * 1024 + n];
            if (OUT_BF16) ((unsigned short*)outp)[(size_t)m * 1024 + n] = f2bf(v);
            else          ((float*)outp)[(size_t)m * 1024 + n] = v;
        }
}

// ---------------- FUSED up->down: up(t_in@BtU) -> epilogue -> (store out) ->
// bounce bf16 tile -> down(@AtD chunk) -> tpout[sp] (+optional sumsq -> sspout)
template<int SILU, int HASBASE, int STOREOUT, int SUMSQ, int DORMS_IN>
__global__ __launch_bounds__(256) void updown_g(const float* __restrict__ tpin,
                                                const float* __restrict__ sspin,
                                                const unsigned short* __restrict__ BtU,
                                                const unsigned short* __restrict__ AtD,
                                                const float* base,
                                                float* outp,
                                                float* __restrict__ tpout,
                                                float* __restrict__ sspout){
    __shared__ char tt[4096];
    __shared__ char bb[32768];     // Bt-up stage, reused for At-down stage
    __shared__ char xb[16384];     // bounced up-output tile [32][256] bf16
    __shared__ float ssl[2][32];
    int tid = threadIdx.x;
    int m0 = blockIdx.x * 32, n0 = blockIdx.y * 256, sp = blockIdx.y;
    int w = tid >> 6, lane = tid & 63, l4 = lane >> 4, lm = lane & 15;
    int wm = w & 1, wn = w >> 1;
    if (tid < 128) stage_t<DORMS_IN>(tt, tpin, sspin, m0, tid);
    {
        const uint4* s = (const uint4*)(BtU + (size_t)(n0 + tid) * 64);
        #pragma unroll
        for (int j = 0; j < 8; ++j){
            uint4 v = s[j];
            *(uint4*)(bb + tid * 128 + ((j * 16) ^ ((tid & 7) << 4))) = v;
        }
    }
    __syncthreads();
    // ---- up MFMA
    bf16x8 af[2];
    #pragma unroll
    for (int ks = 0; ks < 2; ++ks){
        int arow = 16 * wm + lm;
        af[ks] = *(const bf16x8*)(tt + arow * 128 + ((ks*64 + l4*16) ^ ((arow & 7) << 4)));
    }
    f32x4 acc[8];
    #pragma unroll
    for (int nt = 0; nt < 8; ++nt) acc[nt] = (f32x4){0.f,0.f,0.f,0.f};
    #pragma unroll
    for (int nt = 0; nt < 8; ++nt){
        int brow = wn * 128 + nt * 16 + lm;
        #pragma unroll
        for (int ks = 0; ks < 2; ++ks){
            bf16x8 bf = *(const bf16x8*)(bb + brow * 128 + ((ks*64 + l4*16) ^ ((brow & 7) << 4)));
            acc[nt] = __builtin_amdgcn_mfma_f32_16x16x32_bf16(af[ks], bf, acc[nt], 0, 0, 0);
        }
    }
    // ---- epilogue into val[], optional out store / sumsq
    float val[8][4];
    float sq[4] = {0.f, 0.f, 0.f, 0.f};
    #pragma unroll
    for (int nt = 0; nt < 8; ++nt)
        #pragma unroll
        for (int r = 0; r < 4; ++r){
            int m = m0 + 16 * wm + 4 * l4 + r;
            int n = n0 + wn * 128 + nt * 16 + lm;
            float v = acc[nt][r];
            if (SILU) v = v / (1.f + __expf(-v));
            if (HASBASE) v += base[(size_t)m * 1024 + n];
            val[nt][r] = v;
            if (STOREOUT) outp[(size_t)m * 1024 + n] = v;
            if (SUMSQ) sq[r] += v * v;
        }
    if (SUMSQ){
        #pragma unroll
        for (int r = 0; r < 4; ++r){
            float s_ = sq[r];
            s_ += __shfl_xor(s_, 1);
            s_ += __shfl_xor(s_, 2);
            s_ += __shfl_xor(s_, 4);
            s_ += __shfl_xor(s_, 8);
            if (lm == 0) ssl[wn][16 * wm + 4 * l4 + r] = s_;
        }
    }
    __syncthreads();   // up bb reads done, ssl visible
    // ---- restage bb with AtD chunk [64 r][256 k] (512B rows, swizzled)
    {
        int row = tid >> 2, q4 = tid & 3;
        const uint4* s = (const uint4*)(AtD + (size_t)row * 1024 + n0 + q4 * 64);
        #pragma unroll
        for (int j = 0; j < 8; ++j){
            uint4 v = s[j];
            int u = q4 * 8 + j;
            *(uint4*)(bb + row * 512 + ((u * 16) ^ ((row & 7) << 4))) = v;
        }
    }
    // ---- bounce val -> xb bf16 [32][256] (512B rows, swizzled)
    #pragma unroll
    for (int nt = 0; nt < 8; ++nt)
        #pragma unroll
        for (int r = 0; r < 4; ++r){
            int mrow = 16 * wm + 4 * l4 + r;
            int cn = wn * 128 + nt * 16 + lm;
            *(unsigned short*)(xb + mrow * 512 + ((cn * 2) ^ ((mrow & 7) << 4))) = f2bf(val[nt][r]);
        }
    __syncthreads();
    if (SUMSQ && tid < 32)
        sspout[sp * Mn + m0 + tid] = ssl[0][tid] + ssl[1][tid];
    // ---- down MFMA: wave w -> m-half (w&1), r-tile pair (w>>1)
    f32x4 acc2[2];
    acc2[0] = (f32x4){0.f,0.f,0.f,0.f};
    acc2[1] = (f32x4){0.f,0.f,0.f,0.f};
    #pragma unroll
    for (int kk = 0; kk < 8; ++kk){
        int arow = 16 * (w & 1) + lm;
        bf16x8 a2 = *(const bf16x8*)(xb + arow * 512 + ((kk * 64 + l4 * 16) ^ ((arow & 7) << 4)));
        #pragma unroll
        for (int j = 0; j < 2; ++j){
            int brow = (2 * (w >> 1) + j) * 16 + lm;
            bf16x8 b2 = *(const bf16x8*)(bb + brow * 512 + ((kk * 64 + l4 * 16) ^ ((brow & 7) << 4)));
            acc2[j] = __builtin_amdgcn_mfma_f32_16x16x32_bf16(a2, b2, acc2[j], 0, 0, 0);
        }
    }
    #pragma unroll
    for (int j = 0; j < 2; ++j)
        #pragma unroll
        for (int r = 0; r < 4; ++r){
            int ml = 16 * (w & 1) + 4 * l4 + r;
            int nc = (2 * (w >> 1) + j) * 16 + lm;
            tpout[(size_t)sp * TSTRIDE + (size_t)(m0 + ml) * 64 + nc] = acc2[j][r];
        }
}

// ---------------- fused QKV up-proj + RoPE; K,V written as pre-swizzled tile images
__global__ __launch_bounds__(256) void qkv_g(const float* __restrict__ tpart,
                                             const float* __restrict__ sspart,
                                             const unsigned short* __restrict__ Btq,
                                             const unsigned short* __restrict__ Btk,
                                             const unsigned short* __restrict__ Btv,
                                             const float2* __restrict__ rt,
                                             unsigned short* __restrict__ qout,
                                             char* __restrict__ Kimg,
                                             char* __restrict__ Vimg){
    __shared__ char tt[8192];
    __shared__ char bb[32768];
    int tid = threadIdx.x;
    int m0 = blockIdx.x * 64, n0 = blockIdx.y * 256;
    int b = m0 >> 11, s0 = m0 & (Sn - 1);
    int h0 = n0 >> 7;
    int w = tid >> 6, lane = tid & 63, l4 = lane >> 4, lm = lane & 15;
    stage_t<1>(tt, tpart, sspart, m0, tid);
    #define STAGE_B(SRC) { const uint4* s = (const uint4*)((SRC) + (size_t)(n0 + tid) * 64); \
        _Pragma("unroll") for (int j = 0; j < 8; ++j){ uint4 v = s[j]; \
            *(uint4*)(bb + tid * 128 + ((j * 16) ^ ((tid & 7) << 4))) = v; } }
    STAGE_B(Btq);
    __syncthreads();
    bf16x8 af[2];
    #pragma unroll
    for (int ks = 0; ks < 2; ++ks){
        int arow = 16 * w + lm;
        af[ks] = *(const bf16x8*)(tt + arow * 128 + ((ks*64 + l4*16) ^ ((arow & 7) << 4)));
    }
    f32x4 acc[16];
    float2 cs[4][4];
    #pragma unroll
    for (int ntb = 0; ntb < 4; ++ntb)
        #pragma unroll
        for (int r = 0; r < 4; ++r)
            cs[ntb][r] = rt[(size_t)(s0 + 16*w + 4*l4 + r) * 64 + ntb * 16 + lm];

    #define MMUL() { _Pragma("unroll") for (int nt = 0; nt < 16; ++nt) acc[nt] = (f32x4){0.f,0.f,0.f,0.f}; \
        _Pragma("unroll") for (int nt = 0; nt < 16; ++nt){ int brow = nt * 16 + lm; \
            _Pragma("unroll") for (int ks = 0; ks < 2; ++ks){ \
                bf16x8 bf = *(const bf16x8*)(bb + brow * 128 + ((ks*64 + l4*16) ^ ((brow & 7) << 4))); \
                acc[nt] = __builtin_amdgcn_mfma_f32_16x16x32_bf16(af[ks], bf, acc[nt], 0, 0, 0); } } }

    #define ROPE() { _Pragma("unroll") for (int g = 0; g < 2; ++g) \
        _Pragma("unroll") for (int ntb = 0; ntb < 4; ++ntb){ int lo = g*8 + ntb, hi = lo + 4; \
            _Pragma("unroll") for (int r = 0; r < 4; ++r){ float2 c = cs[ntb][r]; \
                float a = acc[lo][r], bq = acc[hi][r]; \
                acc[lo][r] = a * c.x + bq * c.y; acc[hi][r] = -a * c.y + bq * c.x; } } }

    #define BOUNCE() { \
        _Pragma("unroll") for (int nt = 0; nt < 16; ++nt) \
            _Pragma("unroll") for (int r = 0; r < 4; ++r){ \
                int nl = nt * 16 + lm, ml2 = 16 * w + 4 * l4 + r; \
                *(unsigned short*)(bb + ml2 * 512 + ((nl * 2) ^ ((ml2 & 7) << 4))) = f2bf(acc[nt][r]); } \
        __syncthreads(); }

    // ---- Q (pre-scaled by 1/sqrt(128)*log2e via Btq)
    MMUL(); ROPE();
    __syncthreads();
    BOUNCE();
    {
        int ml = tid >> 2, seg = tid & 3;
        int head = h0 + (seg >> 1), hd0q = (seg & 1) * 64;
        size_t dstbase = (((size_t)(b * 8 + head) * Sn + (s0 + ml)) * 128 + hd0q);
        #pragma unroll
        for (int j = 0; j < 8; ++j){
            uint4 v = *(const uint4*)(bb + ml * 512 + ((seg * 128 + j * 16) ^ ((ml & 7) << 4)));
            *(uint4*)(qout + dstbase + j * 8) = v;
        }
    }
    __syncthreads();
    // ---- K -> permuted swizzled tile image
    STAGE_B(Btk);
    __syncthreads();
    MMUL(); ROPE();
    __syncthreads();
    BOUNCE();
    {
        int ml = tid >> 2, seg = tid & 3;
        int hd0q = (seg & 1) * 64;
        int head = h0 + (seg >> 1);
        int pr = 16 * (ml & 3) + (ml >> 2);
        size_t rowb = (((size_t)(b * 8 + head) * 32 + (s0 >> 6)) * 64 + pr) * 256;
        #pragma unroll
        for (int j = 0; j < 8; ++j){
            uint4 v = *(const uint4*)(bb + ml * 512 + ((seg * 128 + j * 16) ^ ((ml & 7) << 4)));
            int cb = hd0q * 2 + j * 16;
            *(uint4*)(Kimg + rowb + (cb ^ ((pr & 7) << 4))) = v;
        }
    }
    __syncthreads();
    // ---- V -> transposed swizzled tile image
    STAGE_B(Btv);
    __syncthreads();
    MMUL();
    __syncthreads();
    #pragma unroll
    for (int nt = 0; nt < 16; ++nt)
        #pragma unroll
        for (int r = 0; r < 4; ++r){
            int nl = nt * 16 + lm, ml2 = 16 * w + 4 * l4 + r;
            *(unsigned short*)(bb + nl * 128 + ((ml2 * 2) ^ ((nl & 7) << 4))) = f2bf(acc[nt][r]);
        }
    __syncthreads();
    {
        int head = h0 + (tid >> 7), d = tid & 127;
        size_t rowb = (((size_t)(b * 8 + head) * 32 + (s0 >> 6)) * 128 + d) * 128;
        #pragma unroll
        for (int j = 0; j < 8; ++j){
            uint4 v = *(const uint4*)(bb + tid * 128 + ((j * 16) ^ ((tid & 7) << 4)));
            *(uint4*)(Vimg + rowb + ((j * 16) ^ ((d & 7) << 4))) = v;
        }
    }
    #undef STAGE_B
    #undef MMUL
    #undef ROPE
    #undef BOUNCE
}

// ---------------- K-split flash attention: static-offset softmax p=2^(s-OFF)
__global__ __launch_bounds__(256, 2) void attn2_kernel(const unsigned short* __restrict__ qb,
                                                       const char* __restrict__ Kimg,
                                                       const char* __restrict__ Vimg,
                                                       unsigned short* __restrict__ ybf,
                                                       float* __restrict__ pacc,
                                                       float* __restrict__ pl){
    __shared__ uint4 smem4[81920 / 16];
    char* smem = (char*)smem4;
    int tid = threadIdx.x;
    int w = tid >> 6, lane = tid & 63, l4 = lane >> 4, lm = lane & 15;
    int i = blockIdx.x;
    int xg = i & 7, j5 = i >> 3;
    int bh = 2 * xg + (j5 & 1);
    int slot = j5 >> 1;
    int grp = slot >> 3, g = slot & 7;
    int J, t0, niters, direct, slice;
    if (grp == 0){ J = 8 + g;  t0 = 0;  niters = 16;         direct = 0; slice = (bh * 8 + g) * 2; }
    else if (grp == 1){ J = 15 - g; t0 = 16; niters = 2 * J - 14; direct = 0; slice = (bh * 8 + (J - 8)) * 2 + 1; }
    else { J = 7 - g;  t0 = 0;  niters = 2 * J + 2;  direct = 1; slice = 0; }
    int b = bh >> 3, h = bh & 7;
    int qrow0w = 128 * J + 32 * w;
    int wqmax = qrow0w + 31;

    bf16x8 qf[2][4];
    #pragma unroll
    for (int f = 0; f < 2; ++f){
        const unsigned short* qg = qb + ((size_t)bh * Sn + qrow0w + 16 * f + lm) * HDn;
        #pragma unroll
        for (int df = 0; df < 4; ++df)
            qf[f][df] = *(const bf16x8*)(qg + df * 32 + l4 * 8);
    }
    f32x4 acc[2][8];
    #pragma unroll
    for (int f = 0; f < 2; ++f)
        #pragma unroll
        for (int dg = 0; dg < 8; ++dg) acc[f][dg] = (f32x4){0.f,0.f,0.f,0.f};
    float lp[2][4];
    #pragma unroll
    for (int f = 0; f < 2; ++f)
        #pragma unroll
        for (int r = 0; r < 4; ++r) lp[f][r] = 0.f;

    const float OFF = 11.541560327111708f;   // 8 * log2(e)
    size_t imgbase = (size_t)bh * 32 * 16384;

    uint4 sk[4], sv4[4];
    {
        size_t tb = imgbase + (size_t)t0 * 16384;
        #pragma unroll
        for (int i2 = 0; i2 < 4; ++i2){
            sk[i2]  = *(const uint4*)(Kimg + tb + i2 * 4096 + tid * 16);
            sv4[i2] = *(const uint4*)(Vimg + tb + i2 * 4096 + tid * 16);
        }
        #pragma unroll
        for (int i2 = 0; i2 < 4; ++i2){
            *(uint4*)(smem + i2 * 4096 + tid * 16) = sk[i2];
            *(uint4*)(smem + 16384 + i2 * 4096 + tid * 16) = sv4[i2];
        }
    }
    __syncthreads();

    for (int it = 0; it < niters; ++it){
        int t = t0 + it;
        int bsel = (it & 1) << 15;
        if (it + 1 < niters){
            size_t tb = imgbase + (size_t)(t + 1) * 16384;
            #pragma unroll
            for (int i2 = 0; i2 < 4; ++i2){
                sk[i2]  = *(const uint4*)(Kimg + tb + i2 * 4096 + tid * 16);
                sv4[i2] = *(const uint4*)(Vimg + tb + i2 * 4096 + tid * 16);
            }
        }
        if (64 * t <= wqmax){
            char* KL = smem + bsel;
            char* VL = smem + bsel + 16384;
            char* pb = smem + 65536 + (w << 12);
            __builtin_amdgcn_s_setprio(1);
            f32x4 sf[2][4];
            #pragma unroll
            for (int kc = 0; kc < 4; ++kc){ sf[0][kc] = (f32x4){0.f,0.f,0.f,0.f}; sf[1][kc] = (f32x4){0.f,0.f,0.f,0.f}; }
            #pragma unroll
            for (int kc = 0; kc < 4; ++kc){
                int krow = 16 * kc + lm;
                int ksw = (krow & 7) << 4;
                #pragma unroll
                for (int df = 0; df < 4; ++df){
                    bf16x8 kf = *(const bf16x8*)(KL + krow * 256 + ((df * 64 + l4 * 16) ^ ksw));
                    sf[0][kc] = __builtin_amdgcn_mfma_f32_16x16x32_bf16(qf[0][df], kf, sf[0][kc], 0, 0, 0);
                    sf[1][kc] = __builtin_amdgcn_mfma_f32_16x16x32_bf16(qf[1][df], kf, sf[1][kc], 0, 0, 0);
                }
            }
            bool needmask = (64 * t + 63 > qrow0w);
            #pragma unroll
            for (int f = 0; f < 2; ++f){
                #pragma unroll
                for (int r = 0; r < 4; ++r){
                    float s0v = sf[f][0][r], s1v = sf[f][1][r],
                          s2v = sf[f][2][r], s3v = sf[f][3][r];
                    if (needmask){
                        int qr = qrow0w + 16 * f + 4 * l4 + r;
                        int j0k = 64 * t + 4 * lm;
                        s0v = (j0k     > qr) ? -1e30f : s0v;
                        s1v = (j0k + 1 > qr) ? -1e30f : s1v;
                        s2v = (j0k + 2 > qr) ? -1e30f : s2v;
                        s3v = (j0k + 3 > qr) ? -1e30f : s3v;
                    }
                    float p0 = vexp2(s0v - OFF), p1 = vexp2(s1v - OFF),
                          p2 = vexp2(s2v - OFF), p3 = vexp2(s3v - OFF);
                    lp[f][r] += p0 + p1 + p2 + p3;
                    int prow = 16 * f + 4 * l4 + r;
                    uint2 pkd = {pk2(p0, p1), pk2(p2, p3)};
                    *(uint2*)(pb + prow * 128 + ((lm * 8) ^ ((prow & 7) << 4))) = pkd;
                }
            }
            #pragma unroll
            for (int ks = 0; ks < 2; ++ks){
                int pcol = (ks * 64 + l4 * 16) ^ ((lm & 7) << 4);
                bf16x8 pa0 = *(const bf16x8*)(pb + lm * 128 + pcol);
                bf16x8 pa1 = *(const bf16x8*)(pb + (16 + lm) * 128 + pcol);
                #pragma unroll
                for (int dg = 0; dg < 8; ++dg){
                    int vrow = 16 * dg + lm;
                    bf16x8 vf = *(const bf16x8*)(VL + vrow * 128 + ((ks * 64 + l4 * 16) ^ ((vrow & 7) << 4)));
                    acc[0][dg] = __builtin_amdgcn_mfma_f32_16x16x32_bf16(pa0, vf, acc[0][dg], 0, 0, 0);
                    acc[1][dg] = __builtin_amdgcn_mfma_f32_16x16x32_bf16(pa1, vf, acc[1][dg], 0, 0, 0);
                }
            }
            __builtin_amdgcn_s_setprio(0);
        }
        if (it + 1 < niters){
            int ob = bsel ^ 32768;
            #pragma unroll
            for (int i2 = 0; i2 < 4; ++i2){
                *(uint4*)(smem + ob + i2 * 4096 + tid * 16) = sk[i2];
                *(uint4*)(smem + ob + 16384 + i2 * 4096 + tid * 16) = sv4[i2];
            }
        }
        __syncthreads();
    }
    float lsum[2][4];
    #pragma unroll
    for (int f = 0; f < 2; ++f)
        #pragma unroll
        for (int r = 0; r < 4; ++r){
            float l_ = lp[f][r];
            l_ += __shfl_xor(l_, 1);
            l_ += __shfl_xor(l_, 2);
            l_ += __shfl_xor(l_, 4);
            l_ += __shfl_xor(l_, 8);
            lsum[f][r] = l_;
        }
    if (direct){
        #pragma unroll
        for (int f = 0; f < 2; ++f)
            #pragma unroll
            for (int r = 0; r < 4; ++r){
                float inv = 1.f / lsum[f][r];
                int row = qrow0w + 16 * f + 4 * l4 + r;
                unsigned short* yr = ybf + ((size_t)b * Sn + row) * Dn + h * HDn;
                #pragma unroll
                for (int dg = 0; dg < 8; ++dg)
                    yr[16 * dg + lm] = f2bf(acc[f][dg][r] * inv);
            }
    } else {
        float* pa_ = pacc + (size_t)slice * 16384;
        #pragma unroll
        for (int f = 0; f < 2; ++f)
            #pragma unroll
            for (int r = 0; r < 4; ++r){
                int row = 32 * w + 16 * f + 4 * l4 + r;
                #pragma unroll
                for (int dg = 0; dg < 8; ++dg)
                    pa_[row * 128 + 16 * dg + lm] = acc[f][dg][r];
                if (lm == 0)
                    pl[slice * 128 + row] = lsum[f][r];
            }
    }
}

// ---------------- combine two K-slices -> y (bf16): O = (A0+A1)/(l0+l1)
__global__ __launch_bounds__(256) void comb_g(const float* __restrict__ pacc,
                                              const float* __restrict__ pl,
                                              unsigned short* __restrict__ ybf){
    int bh = blockIdx.x >> 3, g = blockIdx.x & 7, J = 8 + g;
    int s0 = (bh * 8 + g) * 2, s1 = s0 + 1;
    int tid = threadIdx.x;
    __shared__ float wsum[128];
    if (tid < 128)
        wsum[tid] = 1.f / (pl[s0 * 128 + tid] + pl[s1 * 128 + tid]);
    __syncthreads();
    int b = bh >> 3, h = bh & 7;
    const float4* p0 = (const float4*)(pacc + (size_t)s0 * 16384);
    const float4* p1 = (const float4*)(pacc + (size_t)s1 * 16384);
    #pragma unroll
    for (int i = 0; i < 16; ++i){
        int idx = i * 256 + tid;
        int row = idx >> 5, c4 = idx & 31;
        float4 a0 = p0[idx], a1 = p1[idx];
        float W = wsum[row];
        ushort4 o;
        o.x = f2bf((a0.x + a1.x) * W);
        o.y = f2bf((a0.y + a1.y) * W);
        o.z = f2bf((a0.z + a1.z) * W);
        o.w = f2bf((a0.w + a1.w) * W);
        int srow = 128 * J + row;
        *(ushort4*)(ybf + ((size_t)b * Sn + srow) * Dn + h * HDn + c4 * 4) = o;
    }
}

extern "C" void kernel_launch(void* const* d_in, const int* in_sizes, int n_in,
                              void* d_out, int out_size, void* d_ws, size_t ws_size,
                              hipStream_t stream){
    const float* x      = (const float*)d_in[0];
    const float* A      = (const float*)d_in[1];
    const float* Bm     = (const float*)d_in[2];
    const float* C_q    = (const float*)d_in[3];
    const float* C_k    = (const float*)d_in[4];
    const float* C_v    = (const float*)d_in[5];
    const float* C_o    = (const float*)d_in[6];
    const float* C_fc   = (const float*)d_in[7];
    const float* C_proj = (const float*)d_in[8];
    const float* scale1 = (const float*)d_in[9];
    const float* scale2 = (const float*)d_in[10];
    float* out = (float*)d_out;

    char* ws = (char*)d_ws;
    size_t off = 0;
    auto alloc = [&](size_t bytes)->char*{ char* p = ws + off; off += (bytes + 255) & ~(size_t)255; return p; };
    unsigned short* qb   = (unsigned short*)alloc((size_t)Mn * Dn * 2);   // 8MB
    char*           Kimg = alloc((size_t)16 * 32 * 16384);                // 8MB
    char*           Vimg = alloc((size_t)16 * 32 * 16384);                // 8MB
    unsigned short* ybf  = (unsigned short*)alloc((size_t)Mn * Dn * 2);   // 8MB
    float*          pacc = (float*)alloc((size_t)256 * 16384 * 4);        // 16MB
    float*          pl   = (float*)alloc((size_t)256 * 128 * 4);          // 128KB
    float*          tpA  = (float*)alloc(4 * TSTRIDE * 4);                // 4MB
    float*          tpB  = (float*)alloc(4 * TSTRIDE * 4);                // 4MB
    float*          sspA = (float*)alloc(4 * (size_t)Mn * 4);             // 64KB
    float*          sspB = (float*)alloc(4 * (size_t)Mn * 4);             // 64KB
    unsigned short* At0  = (unsigned short*)alloc(65536 * 2);
    unsigned short* At1  = (unsigned short*)alloc(65536 * 2);
    unsigned short* At2  = (unsigned short*)alloc(65536 * 2);
    unsigned short* Btq  = (unsigned short*)alloc(65536 * 2);
    unsigned short* Btk  = (unsigned short*)alloc(65536 * 2);
    unsigned short* Btv  = (unsigned short*)alloc(65536 * 2);
    unsigned short* Bto  = (unsigned short*)alloc(65536 * 2);
    unsigned short* Btfc = (unsigned short*)alloc(65536 * 2);
    unsigned short* Btpr = (unsigned short*)alloc(65536 * 2);
    float2*         rt   = (float2*)alloc((size_t)Sn * 64 * 8);           // 1MB

    prep_g<<<2816, 256, 0, stream>>>(A, Bm, C_q, C_k, C_v, C_o, C_fc, C_proj,
                                     scale1, scale2, At0, At1, At2,
                                     Btq, Btk, Btv, Bto, Btfc, Btpr, rt);
    // t1 partials = x @ At1 (s1 folded), ss = rowwise sumsq(x)
    down_g<0, 1><<<dim3(Mn / 64, 4), 256, 0, stream>>>(x, At1, tpA, sspA);
    // q (scaled+roped), K-image, V-image (rms fused in staging)
    qkv_g<<<dim3(Mn / 64, 4), 256, 0, stream>>>(tpA, sspA, Btq, Btk, Btv, rt, qb, Kimg, Vimg);
    // attention + combine
    attn2_kernel<<<384, 256, 0, stream>>>(qb, Kimg, Vimg, ybf, pacc, pl);
    comb_g<<<128, 256, 0, stream>>>(pacc, pl, ybf);
    // t2 partials = y @ At0
    down_g<1, 0><<<dim3(Mn / 64, 4), 256, 0, stream>>>(ybf, At0, tpA, nullptr);
    // FUSED: x1 = x + t2@Bto -> out; sumsq(x1) -> sspB; t3 = x1@At2 -> tpB
    updown_g<0, 1, 1, 1, 0><<<dim3(Mn / 32, 4), 256, 0, stream>>>(
        tpA, nullptr, Bto, At2, x, out, tpB, sspB);
    // FUSED: m = silu(rms(t3)@Btfc) (never stored); t4 = m@At0 -> tpA
    updown_g<1, 0, 0, 0, 1><<<dim3(Mn / 32, 4), 256, 0, stream>>>(
        tpB, sspB, Btfc, At0, nullptr, nullptr, tpA, nullptr);
    // out = x1 + t4 @ Btpr
    up_g<0, 1, 0, 0><<<dim3(Mn / 32, 4), 256, 0, stream>>>(tpA, nullptr, Btpr, out, out);
}